// Round 9
// baseline (242.541 us; speedup 1.0000x reference)
//
#include <hip/hip_runtime.h>
#include <hip/hip_bf16.h>

#define NPIX 4096   // H*W
#define NCH  256    // input channels
#define CI   128    // inter channels
#define EPS  1e-5f
#define SOFF 20.0f  // fixed softmax offset (cancels in normalization)

typedef unsigned short u16;
typedef __attribute__((ext_vector_type(8))) short short8;   // 8 bf16 (4 VGPRs)
typedef __attribute__((ext_vector_type(4))) float f32x4;    // MFMA C/D

// ---------- bf16 bit helpers ----------
__device__ __forceinline__ float bfu2f(u16 u) {
    union { unsigned int i; float f; } x; x.i = ((unsigned int)u) << 16; return x.f;
}
__device__ __forceinline__ u16 f2bfu(float f) {
    union { float ff; unsigned int i; } x; x.ff = f;
    unsigned int r = x.i + 0x7FFFu + ((x.i >> 16) & 1u);
    return (u16)(r >> 16);
}

// async global->LDS DMA, 16B per lane; dest = wave-uniform base + lane*16
__device__ __forceinline__ void gload16(const u16* g, u16* l) {
    __builtin_amdgcn_global_load_lds(
        (const __attribute__((address_space(1))) unsigned int*)g,
        (__attribute__((address_space(3))) unsigned int*)l,
        16, 0, 0);
}

// =====================================================================
// Kernel 0: merged weight prep.
// =====================================================================
__global__ __launch_bounds__(256) void prep_kernel(
    const float* __restrict__ w_v,
    const float* __restrict__ w_k1, const float* __restrict__ w_q1,
    const float* __restrict__ w_k2, const float* __restrict__ w_q2,
    const float* __restrict__ w_ts, const float* __restrict__ w_tq,
    u16* __restrict__ Wbf,
    const float* __restrict__ w_cat, u16* __restrict__ wT)
{
    const int bx = blockIdx.x;
    if (bx < 768) {
        int idx = bx * 256 + threadIdx.x;
        int src = idx / 98304;
        int r   = idx - src * 98304;
        int o   = r >> 8, c = r & 255;
        float v;
        if (o < 128)      v = w_v[(size_t)o * 256 + c];
        else if (o < 192) v = (src ? w_k2 : w_k1)[(size_t)(o - 128) * 256 + c];
        else if (o < 256) v = (src ? w_q2 : w_q1)[(size_t)(o - 192) * 256 + c];
        else              v = (src ? w_ts : w_tq)[(size_t)(o - 256) * 256 + c];
        Wbf[idx] = f2bfu(v);
    } else {
        int co = bx - 768;
        const float* srcb = w_cat + (size_t)co * 2304;
        u16* dstb = wT + (size_t)co * 2304;
        for (int t = threadIdx.x; t < 2304; t += 256) {
            int ic = t / 9, tap = t - ic * 9;
            dstb[tap * 256 + ic] = f2bfu(srcb[t]);
        }
    }
}

// =====================================================================
// Kernel 1: MFMA proj GEMM; stages fp32 q/s directly (unchanged).
// =====================================================================
__global__ __launch_bounds__(256) void proj2_kernel(
    const float* __restrict__ xq, const float* __restrict__ xs,
    const u16* __restrict__ Wbf,
    const float* __restrict__ b_v,
    const float* __restrict__ b_k1, const float* __restrict__ b_q1,
    const float* __restrict__ b_k2, const float* __restrict__ b_q2,
    const float* __restrict__ b_ts, const float* __restrict__ g_ts,
    const float* __restrict__ be_ts, const float* __restrict__ m_ts,
    const float* __restrict__ v_ts,
    const float* __restrict__ b_tq, const float* __restrict__ g_tq,
    const float* __restrict__ be_tq, const float* __restrict__ m_tq,
    const float* __restrict__ v_tq,
    u16* __restrict__ kT, u16* __restrict__ qT,
    u16* __restrict__ vq, u16* __restrict__ vs,
    u16* __restrict__ tq, u16* __restrict__ ts)
{
    __shared__ u16 Xs[64 * 264];
    __shared__ u16 KQ[64 * 136];

    const int tid  = threadIdx.x;
    const int lane = tid & 63;
    const int wid  = tid >> 6;
    const int l16  = lane & 15;
    const int quad = lane >> 4;

    const int n0  = blockIdx.x * 64;
    const int bz  = blockIdx.z;
    const int b   = bz >> 1, src = bz & 1;

    const float* xg = (src ? xs : xq) + (size_t)b * NCH * NPIX + n0;
    #pragma unroll
    for (int k0 = 0; k0 < 64; k0 += 16) {
        float v[16];
        #pragma unroll
        for (int k = 0; k < 16; ++k) {
            int idx = tid + (k0 + k) * 256;
            int c = idx >> 6, n = idx & 63;
            v[k] = xg[(size_t)c * NPIX + n];
        }
        #pragma unroll
        for (int k = 0; k < 16; ++k) {
            int idx = tid + (k0 + k) * 256;
            int c = idx >> 6, n = idx & 63;
            Xs[n * 264 + c] = f2bfu(v[k]);
        }
    }
    __syncthreads();

    const u16* W = Wbf + (size_t)src * 384 * 256;
    const int o0w = wid * 96;
    const float* bk = src ? b_k2 : b_k1;
    const float* bq = src ? b_q2 : b_q1;
    const float* bt = src ? b_ts : b_tq;

    f32x4 acc[24];
    #pragma unroll
    for (int ot = 0; ot < 6; ++ot) {
        int ob = o0w + ot * 16 + quad * 4;
        const float* bp;
        if (ob < 128)      bp = b_v + ob;
        else if (ob < 192) bp = bk + (ob - 128);
        else if (ob < 256) bp = bq + (ob - 192);
        else               bp = bt + (ob - 256);
        float4 b4 = *(const float4*)bp;
        f32x4 iv = (f32x4){b4.x, b4.y, b4.z, b4.w};
        #pragma unroll
        for (int pt = 0; pt < 4; ++pt) acc[ot * 4 + pt] = iv;
    }

    #pragma unroll
    for (int kc = 0; kc < 8; ++kc) {
        short8 bfr[4];
        #pragma unroll
        for (int pt = 0; pt < 4; ++pt)
            bfr[pt] = *(const short8*)&Xs[(pt * 16 + l16) * 264 + kc * 32 + quad * 8];
        #pragma unroll
        for (int ot = 0; ot < 6; ++ot) {
            short8 a = *(const short8*)&W[(size_t)(o0w + ot * 16 + l16) * 256 + kc * 32 + quad * 8];
            #pragma unroll
            for (int pt = 0; pt < 4; ++pt)
                acc[ot * 4 + pt] = __builtin_amdgcn_mfma_f32_16x16x32_bf16(a, bfr[pt], acc[ot * 4 + pt], 0, 0, 0);
        }
    }

    #pragma unroll
    for (int ot = 0; ot < 6; ++ot) {
        int ob = o0w + ot * 16;
        #pragma unroll
        for (int pt = 0; pt < 4; ++pt) {
            int px = pt * 16 + l16;
            f32x4 v4 = acc[ot * 4 + pt];
            if (ob < 128) {
                u16* dst = src ? vs : vq;
                #pragma unroll
                for (int r = 0; r < 4; ++r)
                    dst[((size_t)b * CI + ob + quad * 4 + r) * NPIX + n0 + px] = f2bfu(v4[r]);
            } else if (ob < 256) {
                int colb = (ob < 192) ? (ob - 128) : (64 + ob - 192);
                #pragma unroll
                for (int r = 0; r < 4; ++r)
                    KQ[px * 136 + colb + quad * 4 + r] = f2bfu(v4[r]);
            } else {
                const float* g  = src ? g_ts  : g_tq;
                const float* be = src ? be_ts : be_tq;
                const float* mm = src ? m_ts  : m_tq;
                const float* vv = src ? v_ts  : v_tq;
                u16* dst = src ? ts : tq;
                #pragma unroll
                for (int r = 0; r < 4; ++r) {
                    int oc = ob - 256 + quad * 4 + r;
                    float inv = g[oc] * rsqrtf(vv[oc] + EPS);
                    dst[((size_t)b * CI + oc) * NPIX + n0 + px] =
                        f2bfu((v4[r] - mm[oc]) * inv + be[oc]);
                }
            }
        }
    }
    __syncthreads();

    const int chb = src ? 64 : 0;
    #pragma unroll
    for (int u = 0; u < 4; ++u) {
        int idx = tid + u * 256;
        int px = idx >> 4, oct = idx & 15;
        uint4 val = *(const uint4*)&KQ[px * 136 + oct * 8];
        if (oct < 8)
            *(uint4*)&kT[((size_t)b * NPIX + n0 + px) * CI + chb + oct * 8] = val;
        else
            *(uint4*)&qT[((size_t)b * NPIX + n0 + px) * CI + chb + (oct - 8) * 8] = val;
    }
}

// =====================================================================
// Kernel 2: dual flash attention, split-m, async-DMA double buffer.
// R9 = R7 kernel BYTE-IDENTICAL (verified at 232.8 µs); only the
// launcher changes (nseg up to 8). 128-q blocks, two 16-row strips per
// wave, kf/bv shared across strips. LDS = 43008 B -> 3 blocks/CU.
// =====================================================================
#define AKS_OFF 0
#define AVT_OFF 8192
#define APS_OFF 16384
#define ASMEM_U16 21504   // 2*4096 (K dbuf) + 2*4096 (V dbuf) + 128*40 (Ps)

__global__ __launch_bounds__(256, 3) void attn_kernel(
    const u16* __restrict__ kT, const u16* __restrict__ qT,
    const u16* __restrict__ vq, const u16* __restrict__ vs,
    u16* __restrict__ Opart, float* __restrict__ Lpart, int nseg)
{
    __shared__ __align__(16) u16 smem[ASMEM_U16];
    u16* Ps = smem + APS_OFF;   // [q-row 128][m 32 + pad8] stride 40

    const int tid  = threadIdx.x;
    const int lane = tid & 63;
    const int wid  = tid >> 6;
    const int l16  = lane & 15;
    const int quad = lane >> 4;
    const int strip = wid * 16;

    const int ntb = blockIdx.x;       // 0..31 (128 q-rows per block)
    const int n0 = ntb * 128;
    const int at = blockIdx.y;
    const int z  = blockIdx.z;
    const int b  = z / nseg;
    const int seg = z - b * nseg;

    const u16* Qg = at ? qT : kT;
    const u16* Kg = at ? kT : qT;
    const u16* Vg = at ? vq : vs;

    // Q fragments for both strips (B-operand for S^T), held in regs
    short8 qf0[4], qf1[4];
    {
        const u16* Qb0 = Qg + ((size_t)b * NPIX + n0 + strip + l16) * CI;
        const u16* Qb1 = Qb0 + (size_t)64 * CI;
        #pragma unroll
        for (int kc = 0; kc < 4; ++kc) {
            qf0[kc] = *(const short8*)&Qb0[kc * 32 + quad * 8];
            qf1[kc] = *(const short8*)&Qb1[kc * 32 + quad * 8];
        }
    }

    f32x4 o0[8], o1[8];
    #pragma unroll
    for (int ct = 0; ct < 8; ++ct) {
        o0[ct] = (f32x4){0.f, 0.f, 0.f, 0.f};
        o1[ct] = (f32x4){0.f, 0.f, 0.f, 0.f};
    }
    float L0 = 0.f, L1 = 0.f;

    const u16* KgB = Kg + (size_t)b * NPIX * CI;
    const u16* VgB = Vg + (size_t)b * CI * NPIX;

    const int mt0 = seg * (128 / nseg);
    const int mt1 = mt0 + (128 / nseg);

    #define ISSUE_TILE(buf, m0_)                                              \
    {                                                                         \
        u16* kb_ = smem + AKS_OFF + (buf) * 4096;                             \
        u16* vb_ = smem + AVT_OFF + (buf) * 4096;                             \
        _Pragma("unroll")                                                     \
        for (int k = 0; k < 2; ++k) {                                         \
            int sb  = k * 256 + wid * 64;                                     \
            int idx = sb + lane;                                              \
            int row = idx >> 4, segp = idx & 15;                              \
            int segg = segp ^ (row & 15);                                     \
            gload16(KgB + (size_t)((m0_) + row) * CI + segg * 8, kb_ + sb * 8); \
        }                                                                     \
        _Pragma("unroll")                                                     \
        for (int k = 0; k < 2; ++k) {                                         \
            int sb  = k * 256 + wid * 64;                                     \
            int idx = sb + lane;                                              \
            int c = idx >> 2, sgp = idx & 3;                                  \
            int sgg = sgp ^ ((c >> 1) & 3);                                   \
            gload16(VgB + (size_t)c * NPIX + (m0_) + sgg * 8, vb_ + sb * 8);  \
        }                                                                     \
    }

    int cur = 0;
    ISSUE_TILE(0, mt0 * 32);

    for (int mt = mt0; mt < mt1; ++mt) {
        __syncthreads();   // vmcnt(0) drain: tile mt landed; prev buf free
        if (mt + 1 < mt1) ISSUE_TILE(1 - cur, (mt + 1) * 32);

        const u16* Ks = smem + AKS_OFF + cur * 4096;
        const u16* Vt = smem + AVT_OFF + cur * 4096;

        // ---- S^T = K Q^T : 2 m-tiles x 2 strips; kf shared ----
        f32x4 sv0[2], sv1[2];
        __builtin_amdgcn_s_setprio(1);
        #pragma unroll
        for (int m2 = 0; m2 < 2; ++m2) {
            f32x4 c0 = (f32x4){0.f, 0.f, 0.f, 0.f};
            f32x4 c1 = (f32x4){0.f, 0.f, 0.f, 0.f};
            #pragma unroll
            for (int kc = 0; kc < 4; ++kc) {
                int s = kc * 4 + quad;
                short8 kf = *(const short8*)&Ks[(m2 * 16 + l16) * 128 + ((s ^ l16) * 8)];
                c0 = __builtin_amdgcn_mfma_f32_16x16x32_bf16(kf, qf0[kc], c0, 0, 0, 0);
                c1 = __builtin_amdgcn_mfma_f32_16x16x32_bf16(kf, qf1[kc], c1, 0, 0, 0);
            }
            sv0[m2] = c0;
            sv1[m2] = c1;
        }
        __builtin_amdgcn_s_setprio(0);

        // ---- no-max softmax, both strips (R4 code x2) ----
        float Lsum0 = 0.f, Lsum1 = 0.f;
        u16* myPs0 = Ps + (strip + l16) * 40;
        u16* myPs1 = Ps + (64 + strip + l16) * 40;
        #pragma unroll
        for (int m2 = 0; m2 < 2; ++m2) {
            float p0 = __expf(sv0[m2][0] - SOFF);
            float p1 = __expf(sv0[m2][1] - SOFF);
            float p2 = __expf(sv0[m2][2] - SOFF);
            float p3 = __expf(sv0[m2][3] - SOFF);
            Lsum0 += (p0 + p1) + (p2 + p3);
            unsigned int r0, r1;
            asm("v_cvt_pk_bf16_f32 %0, %1, %2" : "=v"(r0) : "v"(p0), "v"(p1));
            asm("v_cvt_pk_bf16_f32 %0, %1, %2" : "=v"(r1) : "v"(p2), "v"(p3));
            uint2 pk; pk.x = r0; pk.y = r1;
            *(uint2*)&myPs0[m2 * 16 + quad * 4] = pk;

            float q0 = __expf(sv1[m2][0] - SOFF);
            float q1 = __expf(sv1[m2][1] - SOFF);
            float q2 = __expf(sv1[m2][2] - SOFF);
            float q3 = __expf(sv1[m2][3] - SOFF);
            Lsum1 += (q0 + q1) + (q2 + q3);
            unsigned int r2, r3;
            asm("v_cvt_pk_bf16_f32 %0, %1, %2" : "=v"(r2) : "v"(q0), "v"(q1));
            asm("v_cvt_pk_bf16_f32 %0, %1, %2" : "=v"(r3) : "v"(q2), "v"(q3));
            uint2 qk; qk.x = r2; qk.y = r3;
            *(uint2*)&myPs1[m2 * 16 + quad * 4] = qk;
        }
        Lsum0 += __shfl_xor(Lsum0, 16);
        Lsum0 += __shfl_xor(Lsum0, 32);
        L0 += Lsum0;
        Lsum1 += __shfl_xor(Lsum1, 16);
        Lsum1 += __shfl_xor(Lsum1, 32);
        L1 += Lsum1;

        // ---- PV both strips; bv shared (Ps rows intra-wave: no barrier) ----
        short8 ap0 = *(const short8*)&Ps[(strip + l16) * 40 + quad * 8];
        short8 ap1 = *(const short8*)&Ps[(64 + strip + l16) * 40 + quad * 8];
        __builtin_amdgcn_s_setprio(1);
        #pragma unroll
        for (int ct = 0; ct < 8; ++ct) {
            int cc = ct * 16 + l16;
            int fc = (cc >> 1) & 3;
            short8 bv = *(const short8*)&Vt[cc * 32 + ((quad ^ fc) * 8)];
            o0[ct] = __builtin_amdgcn_mfma_f32_16x16x32_bf16(ap0, bv, o0[ct], 0, 0, 0);
            o1[ct] = __builtin_amdgcn_mfma_f32_16x16x32_bf16(ap1, bv, o1[ct], 0, 0, 0);
        }
        __builtin_amdgcn_s_setprio(0);
        cur ^= 1;
    }

    // ---- store partials: two 64-row tiles (combine kernel unchanged) ----
    const size_t tile0 = (((size_t)(at * 2 + b) * 64 + 2 * ntb)     * nseg + seg);
    const size_t tile1 = (((size_t)(at * 2 + b) * 64 + 2 * ntb + 1) * nseg + seg);
    u16* Ob0 = Opart + tile0 * 8192;
    u16* Ob1 = Opart + tile1 * 8192;
    #pragma unroll
    for (int r = 0; r < 4; ++r) {
        int row = strip + quad * 4 + r;
        #pragma unroll
        for (int ct = 0; ct < 8; ++ct) {
            Ob0[row * 128 + ct * 16 + l16] = f2bfu(o0[ct][r]);
            Ob1[row * 128 + ct * 16 + l16] = f2bfu(o1[ct][r]);
        }
    }
    if (quad == 0) {
        Lpart[tile0 * 64 + strip + l16] = L0;
        Lpart[tile1 * 64 + strip + l16] = L1;
    }
    #undef ISSUE_TILE
}

// =====================================================================
// Kernel 2b: combine split-m partials (plain sum / sum-L) + epilogue.
// =====================================================================
__global__ __launch_bounds__(256) void attn_combine_kernel(
    const u16* __restrict__ Opart, const float* __restrict__ Lpart,
    const u16* __restrict__ tq, const u16* __restrict__ ts,
    const float* __restrict__ scale_p,
    float* __restrict__ out, u16* __restrict__ Ebf, int nseg)
{
    __shared__ float Of[128 * 68];
    __shared__ float invL[64];

    const int tid = threadIdx.x;
    const int nt = blockIdx.x;
    const int n0 = nt * 64;
    const int at = blockIdx.y;
    const int b  = blockIdx.z;

    const u16* Tg = at ? tq : ts;
    float* outE   = out + (size_t)(at ? 1 : 2) * 1048576;
    const int ch0 = at ? 0 : 128;
    const size_t tbase = ((size_t)(at * 2 + b) * 64 + nt) * nseg;

    if (tid < 64) {
        float Lg = 0.f;
        for (int s = 0; s < nseg; ++s) Lg += Lpart[(tbase + s) * 64 + tid];
        invL[tid] = 1.f / Lg;
    }
    __syncthreads();

    #pragma unroll
    for (int k = 0; k < 4; ++k) {
        int idx = tid + k * 256;
        int row = idx >> 4, oct = idx & 15;
        float m[8] = {0.f, 0.f, 0.f, 0.f, 0.f, 0.f, 0.f, 0.f};
        for (int s = 0; s < nseg; ++s) {
            union { uint4 v; u16 u[8]; } pk;
            pk.v = *(const uint4*)&Opart[(tbase + s) * 8192 + row * 128 + oct * 8];
            #pragma unroll
            for (int j = 0; j < 8; ++j) m[j] += bfu2f(pk.u[j]);
        }
        float w = invL[row];
        #pragma unroll
        for (int j = 0; j < 8; ++j)
            Of[(oct * 8 + j) * 68 + row] = m[j] * w;
    }
    __syncthreads();

    float scale = *scale_p;
    const u16* Tb = Tg + (size_t)b * CI * NPIX + n0;
    float* Ob = outE + (size_t)b * CI * NPIX + n0;
    for (int idx = tid; idx < 128 * 64; idx += 256) {
        int c = idx >> 6, r = idx & 63;
        float v = scale * Of[c * 68 + r] + bfu2f(Tb[(size_t)c * NPIX + r]);
        Ob[(size_t)c * NPIX + r] = v;
        Ebf[((size_t)b * NPIX + n0 + r) * NCH + ch0 + c] = f2bfu(v);
    }
}

// =====================================================================
// Kernel 3: 3x3 conv MFMA implicit GEMM, BARRIER-FREE (unchanged).
// =====================================================================
#define CXT_STR 40

__global__ __launch_bounds__(256) void conv_kernel(
    const u16* __restrict__ Ebf,
    const u16* __restrict__ wT,
    const float* __restrict__ g_cat, const float* __restrict__ be_cat,
    const float* __restrict__ m_cat, const float* __restrict__ v_cat,
    float* __restrict__ out)
{
    __shared__ u16 XtW[4][3 * 34 * CXT_STR];   // per-wave private slices

    const int tid  = threadIdx.x;
    const int lane = tid & 63;
    const int wid  = tid >> 6;
    const int l16  = lane & 15;
    const int quad = lane >> 4;

    const int h    = blockIdx.x;
    const int coff = blockIdx.y * 32;     // 0,32,64,96
    const int b    = blockIdx.z;

    const int cot = wid >> 1;             // co tile (16) within block
    const int pxt = (wid & 1) * 2;        // px tiles {pxt, pxt+1}
    const int gc0 = pxt * 16 - 1;         // global col of local x=0

    f32x4 acc[2];
    #pragma unroll
    for (int j = 0; j < 2; ++j) acc[j] = (f32x4){0.f, 0.f, 0.f, 0.f};

    const u16* Eb = Ebf + (size_t)b * NPIX * NCH;
    u16* Xw = &XtW[wid][0];
    const int cobase = coff + cot * 16 + l16;

    for (int icc = 0; icc < 8; ++icc) {
        const int ic0 = icc * 32;

        // weight fragments (L2-resident, independent loads)
        short8 wfrag[9];
        #pragma unroll
        for (int tap = 0; tap < 9; ++tap)
            wfrag[tap] = *(const short8*)&wT[((size_t)cobase * 9 + tap) * 256 + ic0 + quad * 8];

        // private staging: 3 rows x 34 cols x 4 parts = 408 uint4 per wave
        for (int u = lane; u < 408; u += 64) {
            int part = u & 3, xe = u >> 2;       // xe 0..101
            int dh = xe / 34, x = xe - dh * 34;  // x 0..33
            int gr = h + dh - 1, gc = gc0 + x;
            uint4 val = make_uint4(0u, 0u, 0u, 0u);
            if ((unsigned)gr < 64u && (unsigned)gc < 64u)
                val = *(const uint4*)&Eb[((size_t)gr * 64 + gc) * NCH + ic0 + part * 8];
            *(uint4*)&Xw[(dh * 34 + x) * CXT_STR + part * 8] = val;
        }

        #pragma unroll
        for (int tap = 0; tap < 9; ++tap) {
            const int dh = tap / 3, dw = tap % 3;
            short8 bf[2];
            #pragma unroll
            for (int j = 0; j < 2; ++j) {
                int x = j * 16 + l16 + dw;        // local col 0..33
                bf[j] = *(const short8*)&Xw[(dh * 34 + x) * CXT_STR + quad * 8];
            }
            #pragma unroll
            for (int j = 0; j < 2; ++j)
                acc[j] = __builtin_amdgcn_mfma_f32_16x16x32_bf16(wfrag[tap], bf[j], acc[j], 0, 0, 0);
        }
    }

    #pragma unroll
    for (int r = 0; r < 4; ++r) {
        int co = coff + cot * 16 + quad * 4 + r;
        float inv = g_cat[co] * rsqrtf(v_cat[co] + EPS);
        float mm  = m_cat[co];
        float be  = be_cat[co];
        #pragma unroll
        for (int j = 0; j < 2; ++j) {
            int wcol = (pxt + j) * 16 + l16;
            float v = (acc[j][r] - mm) * inv + be;
            out[((size_t)b * CI + co) * NPIX + h * 64 + wcol] = fmaxf(v, 0.f);
        }
    }
}

// =====================================================================
extern "C" void kernel_launch(void* const* d_in, const int* in_sizes, int n_in,
                              void* d_out, int out_size, void* d_ws, size_t ws_size,
                              hipStream_t stream)
{
    const float* q     = (const float*)d_in[0];
    const float* s     = (const float*)d_in[1];
    const float* scale = (const float*)d_in[2];
    const float* w_v   = (const float*)d_in[3];
    const float* b_v   = (const float*)d_in[4];
    const float* w_k1  = (const float*)d_in[5];
    const float* b_k1  = (const float*)d_in[6];
    const float* w_q1  = (const float*)d_in[7];
    const float* b_q1  = (const float*)d_in[8];
    const float* w_k2  = (const float*)d_in[9];
    const float* b_k2  = (const float*)d_in[10];
    const float* w_q2  = (const float*)d_in[11];
    const float* b_q2  = (const float*)d_in[12];
    const float* w_ts  = (const float*)d_in[13];
    const float* b_ts  = (const float*)d_in[14];
    const float* g_ts  = (const float*)d_in[15];
    const float* be_ts = (const float*)d_in[16];
    const float* m_ts  = (const float*)d_in[17];
    const float* v_ts  = (const float*)d_in[18];
    const float* w_tq  = (const float*)d_in[19];
    const float* b_tq  = (const float*)d_in[20];
    const float* g_tq  = (const float*)d_in[21];
    const float* be_tq = (const float*)d_in[22];
    const float* m_tq  = (const float*)d_in[23];
    const float* v_tq  = (const float*)d_in[24];
    const float* w_cat = (const float*)d_in[25];
    const float* g_cat = (const float*)d_in[26];
    const float* be_cat= (const float*)d_in[27];
    const float* m_cat = (const float*)d_in[28];
    const float* v_cat = (const float*)d_in[29];

    float* out = (float*)d_out;
    u16* ws = (u16*)d_ws;
    const size_t SZ = (size_t)2 * CI * NPIX;        // 1,048,576 u16 per buffer
    u16* kT  = ws;
    u16* qT  = kT + SZ;
    u16* vq  = qT + SZ;
    u16* vs  = vq + SZ;
    u16* tq  = vs + SZ;
    u16* ts  = tq + SZ;
    u16* Wbf = ts + SZ;
    u16* B   = Wbf + 196608;
    u16* Ebf = B;
    u16* wTc = B + 2097152;
    u16* Opart = wTc + 294912;

    const size_t fixed_u16 = 6 * SZ + 196608 + 2097152 + 294912;
    int nseg = 1;
    {
        size_t need8 = (fixed_u16 + (size_t)8 * 2097152) * 2 + (size_t)8 * 131072;
        size_t need4 = (fixed_u16 + (size_t)4 * 2097152) * 2 + (size_t)4 * 131072;
        size_t need2 = (fixed_u16 + (size_t)2 * 2097152) * 2 + (size_t)2 * 131072;
        if (ws_size >= need8)      nseg = 8;
        else if (ws_size >= need4) nseg = 4;
        else if (ws_size >= need2) nseg = 2;
    }
    float* Lpart = (float*)(Opart + (size_t)nseg * 256 * 8192);

    dim3 blk(256);
    hipLaunchKernelGGL(prep_kernel, dim3(896), blk, 0, stream,
                       w_v, w_k1, w_q1, w_k2, w_q2, w_ts, w_tq, Wbf, w_cat, wTc);
    hipLaunchKernelGGL(proj2_kernel, dim3(64, 1, 4), blk, 0, stream,
                       q, s, Wbf, b_v, b_k1, b_q1, b_k2, b_q2,
                       b_ts, g_ts, be_ts, m_ts, v_ts,
                       b_tq, g_tq, be_tq, m_tq, v_tq,
                       kT, qT, vq, vs, tq, ts);
    hipLaunchKernelGGL(attn_kernel, dim3(32, 2, 2 * nseg), blk, 0, stream,
                       kT, qT, vq, vs, Opart, Lpart, nseg);
    hipLaunchKernelGGL(attn_combine_kernel, dim3(64, 2, 2), blk, 0, stream,
                       Opart, Lpart, tq, ts, scale, out, Ebf, nseg);
    hipLaunchKernelGGL(conv_kernel, dim3(64, 4, 2), blk, 0, stream,
                       Ebf, wTc, g_cat, be_cat, m_cat, v_cat, out);
}

// Round 10
// 240.562 us; speedup vs baseline: 1.0082x; 1.0082x over previous
//
#include <hip/hip_runtime.h>
#include <hip/hip_bf16.h>

#define NPIX 4096   // H*W
#define NCH  256    // input channels
#define CI   128    // inter channels
#define EPS  1e-5f
#define SOFF 20.0f  // fixed softmax offset (cancels in normalization)

typedef unsigned short u16;
typedef __attribute__((ext_vector_type(8))) short short8;   // 8 bf16 (4 VGPRs)
typedef __attribute__((ext_vector_type(4))) float f32x4;    // MFMA C/D

// ---------- bf16 bit helpers ----------
__device__ __forceinline__ float bfu2f(u16 u) {
    union { unsigned int i; float f; } x; x.i = ((unsigned int)u) << 16; return x.f;
}
__device__ __forceinline__ u16 f2bfu(float f) {
    union { float ff; unsigned int i; } x; x.ff = f;
    unsigned int r = x.i + 0x7FFFu + ((x.i >> 16) & 1u);
    return (u16)(r >> 16);
}

// async global->LDS DMA, 16B per lane; dest = wave-uniform base + lane*16
__device__ __forceinline__ void gload16(const u16* g, u16* l) {
    __builtin_amdgcn_global_load_lds(
        (const __attribute__((address_space(1))) unsigned int*)g,
        (__attribute__((address_space(3))) unsigned int*)l,
        16, 0, 0);
}

// =====================================================================
// Kernel 0: merged weight prep.
// =====================================================================
__global__ __launch_bounds__(256) void prep_kernel(
    const float* __restrict__ w_v,
    const float* __restrict__ w_k1, const float* __restrict__ w_q1,
    const float* __restrict__ w_k2, const float* __restrict__ w_q2,
    const float* __restrict__ w_ts, const float* __restrict__ w_tq,
    u16* __restrict__ Wbf,
    const float* __restrict__ w_cat, u16* __restrict__ wT)
{
    const int bx = blockIdx.x;
    if (bx < 768) {
        int idx = bx * 256 + threadIdx.x;
        int src = idx / 98304;
        int r   = idx - src * 98304;
        int o   = r >> 8, c = r & 255;
        float v;
        if (o < 128)      v = w_v[(size_t)o * 256 + c];
        else if (o < 192) v = (src ? w_k2 : w_k1)[(size_t)(o - 128) * 256 + c];
        else if (o < 256) v = (src ? w_q2 : w_q1)[(size_t)(o - 192) * 256 + c];
        else              v = (src ? w_ts : w_tq)[(size_t)(o - 256) * 256 + c];
        Wbf[idx] = f2bfu(v);
    } else {
        int co = bx - 768;
        const float* srcb = w_cat + (size_t)co * 2304;
        u16* dstb = wT + (size_t)co * 2304;
        for (int t = threadIdx.x; t < 2304; t += 256) {
            int ic = t / 9, tap = t - ic * 9;
            dstb[tap * 256 + ic] = f2bfu(srcb[t]);
        }
    }
}

// =====================================================================
// Kernel 1: MFMA proj GEMM; stages fp32 q/s directly (unchanged).
// =====================================================================
__global__ __launch_bounds__(256) void proj2_kernel(
    const float* __restrict__ xq, const float* __restrict__ xs,
    const u16* __restrict__ Wbf,
    const float* __restrict__ b_v,
    const float* __restrict__ b_k1, const float* __restrict__ b_q1,
    const float* __restrict__ b_k2, const float* __restrict__ b_q2,
    const float* __restrict__ b_ts, const float* __restrict__ g_ts,
    const float* __restrict__ be_ts, const float* __restrict__ m_ts,
    const float* __restrict__ v_ts,
    const float* __restrict__ b_tq, const float* __restrict__ g_tq,
    const float* __restrict__ be_tq, const float* __restrict__ m_tq,
    const float* __restrict__ v_tq,
    u16* __restrict__ kT, u16* __restrict__ qT,
    u16* __restrict__ vq, u16* __restrict__ vs,
    u16* __restrict__ tq, u16* __restrict__ ts)
{
    __shared__ u16 Xs[64 * 264];
    __shared__ u16 KQ[64 * 136];

    const int tid  = threadIdx.x;
    const int lane = tid & 63;
    const int wid  = tid >> 6;
    const int l16  = lane & 15;
    const int quad = lane >> 4;

    const int n0  = blockIdx.x * 64;
    const int bz  = blockIdx.z;
    const int b   = bz >> 1, src = bz & 1;

    const float* xg = (src ? xs : xq) + (size_t)b * NCH * NPIX + n0;
    #pragma unroll
    for (int k0 = 0; k0 < 64; k0 += 16) {
        float v[16];
        #pragma unroll
        for (int k = 0; k < 16; ++k) {
            int idx = tid + (k0 + k) * 256;
            int c = idx >> 6, n = idx & 63;
            v[k] = xg[(size_t)c * NPIX + n];
        }
        #pragma unroll
        for (int k = 0; k < 16; ++k) {
            int idx = tid + (k0 + k) * 256;
            int c = idx >> 6, n = idx & 63;
            Xs[n * 264 + c] = f2bfu(v[k]);
        }
    }
    __syncthreads();

    const u16* W = Wbf + (size_t)src * 384 * 256;
    const int o0w = wid * 96;
    const float* bk = src ? b_k2 : b_k1;
    const float* bq = src ? b_q2 : b_q1;
    const float* bt = src ? b_ts : b_tq;

    f32x4 acc[24];
    #pragma unroll
    for (int ot = 0; ot < 6; ++ot) {
        int ob = o0w + ot * 16 + quad * 4;
        const float* bp;
        if (ob < 128)      bp = b_v + ob;
        else if (ob < 192) bp = bk + (ob - 128);
        else if (ob < 256) bp = bq + (ob - 192);
        else               bp = bt + (ob - 256);
        float4 b4 = *(const float4*)bp;
        f32x4 iv = (f32x4){b4.x, b4.y, b4.z, b4.w};
        #pragma unroll
        for (int pt = 0; pt < 4; ++pt) acc[ot * 4 + pt] = iv;
    }

    #pragma unroll
    for (int kc = 0; kc < 8; ++kc) {
        short8 bfr[4];
        #pragma unroll
        for (int pt = 0; pt < 4; ++pt)
            bfr[pt] = *(const short8*)&Xs[(pt * 16 + l16) * 264 + kc * 32 + quad * 8];
        #pragma unroll
        for (int ot = 0; ot < 6; ++ot) {
            short8 a = *(const short8*)&W[(size_t)(o0w + ot * 16 + l16) * 256 + kc * 32 + quad * 8];
            #pragma unroll
            for (int pt = 0; pt < 4; ++pt)
                acc[ot * 4 + pt] = __builtin_amdgcn_mfma_f32_16x16x32_bf16(a, bfr[pt], acc[ot * 4 + pt], 0, 0, 0);
        }
    }

    #pragma unroll
    for (int ot = 0; ot < 6; ++ot) {
        int ob = o0w + ot * 16;
        #pragma unroll
        for (int pt = 0; pt < 4; ++pt) {
            int px = pt * 16 + l16;
            f32x4 v4 = acc[ot * 4 + pt];
            if (ob < 128) {
                u16* dst = src ? vs : vq;
                #pragma unroll
                for (int r = 0; r < 4; ++r)
                    dst[((size_t)b * CI + ob + quad * 4 + r) * NPIX + n0 + px] = f2bfu(v4[r]);
            } else if (ob < 256) {
                int colb = (ob < 192) ? (ob - 128) : (64 + ob - 192);
                #pragma unroll
                for (int r = 0; r < 4; ++r)
                    KQ[px * 136 + colb + quad * 4 + r] = f2bfu(v4[r]);
            } else {
                const float* g  = src ? g_ts  : g_tq;
                const float* be = src ? be_ts : be_tq;
                const float* mm = src ? m_ts  : m_tq;
                const float* vv = src ? v_ts  : v_tq;
                u16* dst = src ? ts : tq;
                #pragma unroll
                for (int r = 0; r < 4; ++r) {
                    int oc = ob - 256 + quad * 4 + r;
                    float inv = g[oc] * rsqrtf(vv[oc] + EPS);
                    dst[((size_t)b * CI + oc) * NPIX + n0 + px] =
                        f2bfu((v4[r] - mm[oc]) * inv + be[oc]);
                }
            }
        }
    }
    __syncthreads();

    const int chb = src ? 64 : 0;
    #pragma unroll
    for (int u = 0; u < 4; ++u) {
        int idx = tid + u * 256;
        int px = idx >> 4, oct = idx & 15;
        uint4 val = *(const uint4*)&KQ[px * 136 + oct * 8];
        if (oct < 8)
            *(uint4*)&kT[((size_t)b * NPIX + n0 + px) * CI + chb + oct * 8] = val;
        else
            *(uint4*)&qT[((size_t)b * NPIX + n0 + px) * CI + chb + (oct - 8) * 8] = val;
    }
}

// =====================================================================
// Kernel 2: dual flash attention, split-m, async-DMA double buffer.
// R7 kernel BYTE-IDENTICAL (verified, 50.4 us @ nseg=4). 128-q blocks,
// two 16-row strips per wave, kf/bv shared. LDS 43008 B -> 3 blocks/CU.
// =====================================================================
#define AKS_OFF 0
#define AVT_OFF 8192
#define APS_OFF 16384
#define ASMEM_U16 21504   // 2*4096 (K dbuf) + 2*4096 (V dbuf) + 128*40 (Ps)

__global__ __launch_bounds__(256, 3) void attn_kernel(
    const u16* __restrict__ kT, const u16* __restrict__ qT,
    const u16* __restrict__ vq, const u16* __restrict__ vs,
    u16* __restrict__ Opart, float* __restrict__ Lpart, int nseg)
{
    __shared__ __align__(16) u16 smem[ASMEM_U16];
    u16* Ps = smem + APS_OFF;   // [q-row 128][m 32 + pad8] stride 40

    const int tid  = threadIdx.x;
    const int lane = tid & 63;
    const int wid  = tid >> 6;
    const int l16  = lane & 15;
    const int quad = lane >> 4;
    const int strip = wid * 16;

    const int ntb = blockIdx.x;       // 0..31 (128 q-rows per block)
    const int n0 = ntb * 128;
    const int at = blockIdx.y;
    const int z  = blockIdx.z;
    const int b  = z / nseg;
    const int seg = z - b * nseg;

    const u16* Qg = at ? qT : kT;
    const u16* Kg = at ? kT : qT;
    const u16* Vg = at ? vq : vs;

    // Q fragments for both strips (B-operand for S^T), held in regs
    short8 qf0[4], qf1[4];
    {
        const u16* Qb0 = Qg + ((size_t)b * NPIX + n0 + strip + l16) * CI;
        const u16* Qb1 = Qb0 + (size_t)64 * CI;
        #pragma unroll
        for (int kc = 0; kc < 4; ++kc) {
            qf0[kc] = *(const short8*)&Qb0[kc * 32 + quad * 8];
            qf1[kc] = *(const short8*)&Qb1[kc * 32 + quad * 8];
        }
    }

    f32x4 o0[8], o1[8];
    #pragma unroll
    for (int ct = 0; ct < 8; ++ct) {
        o0[ct] = (f32x4){0.f, 0.f, 0.f, 0.f};
        o1[ct] = (f32x4){0.f, 0.f, 0.f, 0.f};
    }
    float L0 = 0.f, L1 = 0.f;

    const u16* KgB = Kg + (size_t)b * NPIX * CI;
    const u16* VgB = Vg + (size_t)b * CI * NPIX;

    const int mt0 = seg * (128 / nseg);
    const int mt1 = mt0 + (128 / nseg);

    #define ISSUE_TILE(buf, m0_)                                              \
    {                                                                         \
        u16* kb_ = smem + AKS_OFF + (buf) * 4096;                             \
        u16* vb_ = smem + AVT_OFF + (buf) * 4096;                             \
        _Pragma("unroll")                                                     \
        for (int k = 0; k < 2; ++k) {                                         \
            int sb  = k * 256 + wid * 64;                                     \
            int idx = sb + lane;                                              \
            int row = idx >> 4, segp = idx & 15;                              \
            int segg = segp ^ (row & 15);                                     \
            gload16(KgB + (size_t)((m0_) + row) * CI + segg * 8, kb_ + sb * 8); \
        }                                                                     \
        _Pragma("unroll")                                                     \
        for (int k = 0; k < 2; ++k) {                                         \
            int sb  = k * 256 + wid * 64;                                     \
            int idx = sb + lane;                                              \
            int c = idx >> 2, sgp = idx & 3;                                  \
            int sgg = sgp ^ ((c >> 1) & 3);                                   \
            gload16(VgB + (size_t)c * NPIX + (m0_) + sgg * 8, vb_ + sb * 8);  \
        }                                                                     \
    }

    int cur = 0;
    ISSUE_TILE(0, mt0 * 32);

    for (int mt = mt0; mt < mt1; ++mt) {
        __syncthreads();   // vmcnt(0) drain: tile mt landed; prev buf free
        if (mt + 1 < mt1) ISSUE_TILE(1 - cur, (mt + 1) * 32);

        const u16* Ks = smem + AKS_OFF + cur * 4096;
        const u16* Vt = smem + AVT_OFF + cur * 4096;

        // ---- S^T = K Q^T : 2 m-tiles x 2 strips; kf shared ----
        f32x4 sv0[2], sv1[2];
        __builtin_amdgcn_s_setprio(1);
        #pragma unroll
        for (int m2 = 0; m2 < 2; ++m2) {
            f32x4 c0 = (f32x4){0.f, 0.f, 0.f, 0.f};
            f32x4 c1 = (f32x4){0.f, 0.f, 0.f, 0.f};
            #pragma unroll
            for (int kc = 0; kc < 4; ++kc) {
                int s = kc * 4 + quad;
                short8 kf = *(const short8*)&Ks[(m2 * 16 + l16) * 128 + ((s ^ l16) * 8)];
                c0 = __builtin_amdgcn_mfma_f32_16x16x32_bf16(kf, qf0[kc], c0, 0, 0, 0);
                c1 = __builtin_amdgcn_mfma_f32_16x16x32_bf16(kf, qf1[kc], c1, 0, 0, 0);
            }
            sv0[m2] = c0;
            sv1[m2] = c1;
        }
        __builtin_amdgcn_s_setprio(0);

        // ---- no-max softmax, both strips ----
        float Lsum0 = 0.f, Lsum1 = 0.f;
        u16* myPs0 = Ps + (strip + l16) * 40;
        u16* myPs1 = Ps + (64 + strip + l16) * 40;
        #pragma unroll
        for (int m2 = 0; m2 < 2; ++m2) {
            float p0 = __expf(sv0[m2][0] - SOFF);
            float p1 = __expf(sv0[m2][1] - SOFF);
            float p2 = __expf(sv0[m2][2] - SOFF);
            float p3 = __expf(sv0[m2][3] - SOFF);
            Lsum0 += (p0 + p1) + (p2 + p3);
            unsigned int r0, r1;
            asm("v_cvt_pk_bf16_f32 %0, %1, %2" : "=v"(r0) : "v"(p0), "v"(p1));
            asm("v_cvt_pk_bf16_f32 %0, %1, %2" : "=v"(r1) : "v"(p2), "v"(p3));
            uint2 pk; pk.x = r0; pk.y = r1;
            *(uint2*)&myPs0[m2 * 16 + quad * 4] = pk;

            float q0 = __expf(sv1[m2][0] - SOFF);
            float q1 = __expf(sv1[m2][1] - SOFF);
            float q2 = __expf(sv1[m2][2] - SOFF);
            float q3 = __expf(sv1[m2][3] - SOFF);
            Lsum1 += (q0 + q1) + (q2 + q3);
            unsigned int r2, r3;
            asm("v_cvt_pk_bf16_f32 %0, %1, %2" : "=v"(r2) : "v"(q0), "v"(q1));
            asm("v_cvt_pk_bf16_f32 %0, %1, %2" : "=v"(r3) : "v"(q2), "v"(q3));
            uint2 qk; qk.x = r2; qk.y = r3;
            *(uint2*)&myPs1[m2 * 16 + quad * 4] = qk;
        }
        Lsum0 += __shfl_xor(Lsum0, 16);
        Lsum0 += __shfl_xor(Lsum0, 32);
        L0 += Lsum0;
        Lsum1 += __shfl_xor(Lsum1, 16);
        Lsum1 += __shfl_xor(Lsum1, 32);
        L1 += Lsum1;

        // ---- PV both strips; bv shared (Ps rows intra-wave: no barrier) ----
        short8 ap0 = *(const short8*)&Ps[(strip + l16) * 40 + quad * 8];
        short8 ap1 = *(const short8*)&Ps[(64 + strip + l16) * 40 + quad * 8];
        __builtin_amdgcn_s_setprio(1);
        #pragma unroll
        for (int ct = 0; ct < 8; ++ct) {
            int cc = ct * 16 + l16;
            int fc = (cc >> 1) & 3;
            short8 bv = *(const short8*)&Vt[cc * 32 + ((quad ^ fc) * 8)];
            o0[ct] = __builtin_amdgcn_mfma_f32_16x16x32_bf16(ap0, bv, o0[ct], 0, 0, 0);
            o1[ct] = __builtin_amdgcn_mfma_f32_16x16x32_bf16(ap1, bv, o1[ct], 0, 0, 0);
        }
        __builtin_amdgcn_s_setprio(0);
        cur ^= 1;
    }

    // ---- store partials: two 64-row tiles (combine kernel unchanged) ----
    const size_t tile0 = (((size_t)(at * 2 + b) * 64 + 2 * ntb)     * nseg + seg);
    const size_t tile1 = (((size_t)(at * 2 + b) * 64 + 2 * ntb + 1) * nseg + seg);
    u16* Ob0 = Opart + tile0 * 8192;
    u16* Ob1 = Opart + tile1 * 8192;
    #pragma unroll
    for (int r = 0; r < 4; ++r) {
        int row = strip + quad * 4 + r;
        #pragma unroll
        for (int ct = 0; ct < 8; ++ct) {
            Ob0[row * 128 + ct * 16 + l16] = f2bfu(o0[ct][r]);
            Ob1[row * 128 + ct * 16 + l16] = f2bfu(o1[ct][r]);
        }
    }
    if (quad == 0) {
        Lpart[tile0 * 64 + strip + l16] = L0;
        Lpart[tile1 * 64 + strip + l16] = L1;
    }
    #undef ISSUE_TILE
}

// =====================================================================
// Kernel 2b: combine split-m partials (plain sum / sum-L) + epilogue.
// =====================================================================
__global__ __launch_bounds__(256) void attn_combine_kernel(
    const u16* __restrict__ Opart, const float* __restrict__ Lpart,
    const u16* __restrict__ tq, const u16* __restrict__ ts,
    const float* __restrict__ scale_p,
    float* __restrict__ out, u16* __restrict__ Ebf, int nseg)
{
    __shared__ float Of[128 * 68];
    __shared__ float invL[64];

    const int tid = threadIdx.x;
    const int nt = blockIdx.x;
    const int n0 = nt * 64;
    const int at = blockIdx.y;
    const int b  = blockIdx.z;

    const u16* Tg = at ? tq : ts;
    float* outE   = out + (size_t)(at ? 1 : 2) * 1048576;
    const int ch0 = at ? 0 : 128;
    const size_t tbase = ((size_t)(at * 2 + b) * 64 + nt) * nseg;

    if (tid < 64) {
        float Lg = 0.f;
        for (int s = 0; s < nseg; ++s) Lg += Lpart[(tbase + s) * 64 + tid];
        invL[tid] = 1.f / Lg;
    }
    __syncthreads();

    #pragma unroll
    for (int k = 0; k < 4; ++k) {
        int idx = tid + k * 256;
        int row = idx >> 4, oct = idx & 15;
        float m[8] = {0.f, 0.f, 0.f, 0.f, 0.f, 0.f, 0.f, 0.f};
        for (int s = 0; s < nseg; ++s) {
            union { uint4 v; u16 u[8]; } pk;
            pk.v = *(const uint4*)&Opart[(tbase + s) * 8192 + row * 128 + oct * 8];
            #pragma unroll
            for (int j = 0; j < 8; ++j) m[j] += bfu2f(pk.u[j]);
        }
        float w = invL[row];
        #pragma unroll
        for (int j = 0; j < 8; ++j)
            Of[(oct * 8 + j) * 68 + row] = m[j] * w;
    }
    __syncthreads();

    float scale = *scale_p;
    const u16* Tb = Tg + (size_t)b * CI * NPIX + n0;
    float* Ob = outE + (size_t)b * CI * NPIX + n0;
    for (int idx = tid; idx < 128 * 64; idx += 256) {
        int c = idx >> 6, r = idx & 63;
        float v = scale * Of[c * 68 + r] + bfu2f(Tb[(size_t)c * NPIX + r]);
        Ob[(size_t)c * NPIX + r] = v;
        Ebf[((size_t)b * NPIX + n0 + r) * NCH + ch0 + c] = f2bfu(v);
    }
}

// =====================================================================
// Kernel 3: 3x3 conv MFMA implicit GEMM, BARRIER-FREE.
// R10: coff blocks merged 4->2 (each block computes 64 co). Staging is
// byte-identical and runs ONCE per icc per wave; the tap loop runs twice
// (co-tiles cot and cot+2) reusing the staged slice. Global staging
// reads halve: 107 MB -> 53.5 MB. Weight frags reloaded per pass to keep
// VGPR flat.
// =====================================================================
#define CXT_STR 40

__global__ __launch_bounds__(256) void conv_kernel(
    const u16* __restrict__ Ebf,
    const u16* __restrict__ wT,
    const float* __restrict__ g_cat, const float* __restrict__ be_cat,
    const float* __restrict__ m_cat, const float* __restrict__ v_cat,
    float* __restrict__ out)
{
    __shared__ u16 XtW[4][3 * 34 * CXT_STR];   // per-wave private slices

    const int tid  = threadIdx.x;
    const int lane = tid & 63;
    const int wid  = tid >> 6;
    const int l16  = lane & 15;
    const int quad = lane >> 4;

    const int h    = blockIdx.x;
    const int coff = blockIdx.y * 64;     // 0,64
    const int b    = blockIdx.z;

    const int cot = wid >> 1;             // first co tile (16) within block
    const int pxt = (wid & 1) * 2;        // px tiles {pxt, pxt+1}
    const int gc0 = pxt * 16 - 1;         // global col of local x=0

    f32x4 accA[2], accB[2];
    #pragma unroll
    for (int j = 0; j < 2; ++j) {
        accA[j] = (f32x4){0.f, 0.f, 0.f, 0.f};
        accB[j] = (f32x4){0.f, 0.f, 0.f, 0.f};
    }

    const u16* Eb = Ebf + (size_t)b * NPIX * NCH;
    u16* Xw = &XtW[wid][0];
    const int cobaseA = coff + cot * 16 + l16;        // co tile cot
    const int cobaseB = cobaseA + 32;                 // co tile cot+2

    for (int icc = 0; icc < 8; ++icc) {
        const int ic0 = icc * 32;

        // private staging (unchanged): 3 rows x 34 cols x 4 parts per wave
        for (int u = lane; u < 408; u += 64) {
            int part = u & 3, xe = u >> 2;       // xe 0..101
            int dh = xe / 34, x = xe - dh * 34;  // x 0..33
            int gr = h + dh - 1, gc = gc0 + x;
            uint4 val = make_uint4(0u, 0u, 0u, 0u);
            if ((unsigned)gr < 64u && (unsigned)gc < 64u)
                val = *(const uint4*)&Eb[((size_t)gr * 64 + gc) * NCH + ic0 + part * 8];
            *(uint4*)&Xw[(dh * 34 + x) * CXT_STR + part * 8] = val;
        }

        // ---- pass A: co tile cot ----
        #pragma unroll
        for (int tap = 0; tap < 9; ++tap) {
            const int dh = tap / 3, dw = tap % 3;
            short8 wf = *(const short8*)&wT[((size_t)cobaseA * 9 + tap) * 256 + ic0 + quad * 8];
            #pragma unroll
            for (int j = 0; j < 2; ++j) {
                int x = j * 16 + l16 + dw;        // local col 0..33
                short8 bf = *(const short8*)&Xw[(dh * 34 + x) * CXT_STR + quad * 8];
                accA[j] = __builtin_amdgcn_mfma_f32_16x16x32_bf16(wf, bf, accA[j], 0, 0, 0);
            }
        }
        // ---- pass B: co tile cot+2, same staged slice ----
        #pragma unroll
        for (int tap = 0; tap < 9; ++tap) {
            const int dh = tap / 3, dw = tap % 3;
            short8 wf = *(const short8*)&wT[((size_t)cobaseB * 9 + tap) * 256 + ic0 + quad * 8];
            #pragma unroll
            for (int j = 0; j < 2; ++j) {
                int x = j * 16 + l16 + dw;
                short8 bf = *(const short8*)&Xw[(dh * 34 + x) * CXT_STR + quad * 8];
                accB[j] = __builtin_amdgcn_mfma_f32_16x16x32_bf16(wf, bf, accB[j], 0, 0, 0);
            }
        }
    }

    #pragma unroll
    for (int r = 0; r < 4; ++r) {
        {
            int co = coff + cot * 16 + quad * 4 + r;
            float inv = g_cat[co] * rsqrtf(v_cat[co] + EPS);
            float mm  = m_cat[co];
            float be  = be_cat[co];
            #pragma unroll
            for (int j = 0; j < 2; ++j) {
                int wcol = (pxt + j) * 16 + l16;
                float v = (accA[j][r] - mm) * inv + be;
                out[((size_t)b * CI + co) * NPIX + h * 64 + wcol] = fmaxf(v, 0.f);
            }
        }
        {
            int co = coff + (cot + 2) * 16 + quad * 4 + r;
            float inv = g_cat[co] * rsqrtf(v_cat[co] + EPS);
            float mm  = m_cat[co];
            float be  = be_cat[co];
            #pragma unroll
            for (int j = 0; j < 2; ++j) {
                int wcol = (pxt + j) * 16 + l16;
                float v = (accB[j][r] - mm) * inv + be;
                out[((size_t)b * CI + co) * NPIX + h * 64 + wcol] = fmaxf(v, 0.f);
            }
        }
    }
}

// =====================================================================
extern "C" void kernel_launch(void* const* d_in, const int* in_sizes, int n_in,
                              void* d_out, int out_size, void* d_ws, size_t ws_size,
                              hipStream_t stream)
{
    const float* q     = (const float*)d_in[0];
    const float* s     = (const float*)d_in[1];
    const float* scale = (const float*)d_in[2];
    const float* w_v   = (const float*)d_in[3];
    const float* b_v   = (const float*)d_in[4];
    const float* w_k1  = (const float*)d_in[5];
    const float* b_k1  = (const float*)d_in[6];
    const float* w_q1  = (const float*)d_in[7];
    const float* b_q1  = (const float*)d_in[8];
    const float* w_k2  = (const float*)d_in[9];
    const float* b_k2  = (const float*)d_in[10];
    const float* w_q2  = (const float*)d_in[11];
    const float* b_q2  = (const float*)d_in[12];
    const float* w_ts  = (const float*)d_in[13];
    const float* b_ts  = (const float*)d_in[14];
    const float* g_ts  = (const float*)d_in[15];
    const float* be_ts = (const float*)d_in[16];
    const float* m_ts  = (const float*)d_in[17];
    const float* v_ts  = (const float*)d_in[18];
    const float* w_tq  = (const float*)d_in[19];
    const float* b_tq  = (const float*)d_in[20];
    const float* g_tq  = (const float*)d_in[21];
    const float* be_tq = (const float*)d_in[22];
    const float* m_tq  = (const float*)d_in[23];
    const float* v_tq  = (const float*)d_in[24];
    const float* w_cat = (const float*)d_in[25];
    const float* g_cat = (const float*)d_in[26];
    const float* be_cat= (const float*)d_in[27];
    const float* m_cat = (const float*)d_in[28];
    const float* v_cat = (const float*)d_in[29];

    float* out = (float*)d_out;
    u16* ws = (u16*)d_ws;
    const size_t SZ = (size_t)2 * CI * NPIX;        // 1,048,576 u16 per buffer
    u16* kT  = ws;
    u16* qT  = kT + SZ;
    u16* vq  = qT + SZ;
    u16* vs  = vq + SZ;
    u16* tq  = vs + SZ;
    u16* ts  = tq + SZ;
    u16* Wbf = ts + SZ;
    u16* B   = Wbf + 196608;
    u16* Ebf = B;
    u16* wTc = B + 2097152;
    u16* Opart = wTc + 294912;

    const size_t fixed_u16 = 6 * SZ + 196608 + 2097152 + 294912;
    int nseg = 1;
    {
        size_t need4 = (fixed_u16 + (size_t)4 * 2097152) * 2 + (size_t)4 * 131072;
        size_t need2 = (fixed_u16 + (size_t)2 * 2097152) * 2 + (size_t)2 * 131072;
        if (ws_size >= need4)      nseg = 4;
        else if (ws_size >= need2) nseg = 2;
    }
    float* Lpart = (float*)(Opart + (size_t)nseg * 256 * 8192);

    dim3 blk(256);
    hipLaunchKernelGGL(prep_kernel, dim3(896), blk, 0, stream,
                       w_v, w_k1, w_q1, w_k2, w_q2, w_ts, w_tq, Wbf, w_cat, wTc);
    hipLaunchKernelGGL(proj2_kernel, dim3(64, 1, 4), blk, 0, stream,
                       q, s, Wbf, b_v, b_k1, b_q1, b_k2, b_q2,
                       b_ts, g_ts, be_ts, m_ts, v_ts,
                       b_tq, g_tq, be_tq, m_tq, v_tq,
                       kT, qT, vq, vs, tq, ts);
    hipLaunchKernelGGL(attn_kernel, dim3(32, 2, 2 * nseg), blk, 0, stream,
                       kT, qT, vq, vs, Opart, Lpart, nseg);
    hipLaunchKernelGGL(attn_combine_kernel, dim3(64, 2, 2), blk, 0, stream,
                       Opart, Lpart, tq, ts, scale, out, Ebf, nseg);
    hipLaunchKernelGGL(conv_kernel, dim3(64, 2, 2), blk, 0, stream,
                       Ebf, wTc, g_cat, be_cat, m_cat, v_cat, out);
}

// Round 11
// 233.735 us; speedup vs baseline: 1.0377x; 1.0292x over previous
//
#include <hip/hip_runtime.h>
#include <hip/hip_bf16.h>

#define NPIX 4096   // H*W
#define NCH  256    // input channels
#define CI   128    // inter channels
#define EPS  1e-5f
#define SOFF 20.0f  // fixed softmax offset (cancels in normalization)

typedef unsigned short u16;
typedef __attribute__((ext_vector_type(8))) short short8;   // 8 bf16 (4 VGPRs)
typedef __attribute__((ext_vector_type(4))) float f32x4;    // MFMA C/D

// ---------- bf16 bit helpers ----------
__device__ __forceinline__ float bfu2f(u16 u) {
    union { unsigned int i; float f; } x; x.i = ((unsigned int)u) << 16; return x.f;
}
__device__ __forceinline__ u16 f2bfu(float f) {
    union { float ff; unsigned int i; } x; x.ff = f;
    unsigned int r = x.i + 0x7FFFu + ((x.i >> 16) & 1u);
    return (u16)(r >> 16);
}

// async global->LDS DMA, 16B per lane; dest = wave-uniform base + lane*16
__device__ __forceinline__ void gload16(const u16* g, u16* l) {
    __builtin_amdgcn_global_load_lds(
        (const __attribute__((address_space(1))) unsigned int*)g,
        (__attribute__((address_space(3))) unsigned int*)l,
        16, 0, 0);
}

// =====================================================================
// Kernel 0: merged weight prep.
// =====================================================================
__global__ __launch_bounds__(256) void prep_kernel(
    const float* __restrict__ w_v,
    const float* __restrict__ w_k1, const float* __restrict__ w_q1,
    const float* __restrict__ w_k2, const float* __restrict__ w_q2,
    const float* __restrict__ w_ts, const float* __restrict__ w_tq,
    u16* __restrict__ Wbf,
    const float* __restrict__ w_cat, u16* __restrict__ wT)
{
    const int bx = blockIdx.x;
    if (bx < 768) {
        int idx = bx * 256 + threadIdx.x;
        int src = idx / 98304;
        int r   = idx - src * 98304;
        int o   = r >> 8, c = r & 255;
        float v;
        if (o < 128)      v = w_v[(size_t)o * 256 + c];
        else if (o < 192) v = (src ? w_k2 : w_k1)[(size_t)(o - 128) * 256 + c];
        else if (o < 256) v = (src ? w_q2 : w_q1)[(size_t)(o - 192) * 256 + c];
        else              v = (src ? w_ts : w_tq)[(size_t)(o - 256) * 256 + c];
        Wbf[idx] = f2bfu(v);
    } else {
        int co = bx - 768;
        const float* srcb = w_cat + (size_t)co * 2304;
        u16* dstb = wT + (size_t)co * 2304;
        for (int t = threadIdx.x; t < 2304; t += 256) {
            int ic = t / 9, tap = t - ic * 9;
            dstb[tap * 256 + ic] = f2bfu(srcb[t]);
        }
    }
}

// =====================================================================
// Kernel 1: MFMA proj GEMM; stages fp32 q/s directly (unchanged).
// =====================================================================
__global__ __launch_bounds__(256) void proj2_kernel(
    const float* __restrict__ xq, const float* __restrict__ xs,
    const u16* __restrict__ Wbf,
    const float* __restrict__ b_v,
    const float* __restrict__ b_k1, const float* __restrict__ b_q1,
    const float* __restrict__ b_k2, const float* __restrict__ b_q2,
    const float* __restrict__ b_ts, const float* __restrict__ g_ts,
    const float* __restrict__ be_ts, const float* __restrict__ m_ts,
    const float* __restrict__ v_ts,
    const float* __restrict__ b_tq, const float* __restrict__ g_tq,
    const float* __restrict__ be_tq, const float* __restrict__ m_tq,
    const float* __restrict__ v_tq,
    u16* __restrict__ kT, u16* __restrict__ qT,
    u16* __restrict__ vq, u16* __restrict__ vs,
    u16* __restrict__ tq, u16* __restrict__ ts)
{
    __shared__ u16 Xs[64 * 264];
    __shared__ u16 KQ[64 * 136];

    const int tid  = threadIdx.x;
    const int lane = tid & 63;
    const int wid  = tid >> 6;
    const int l16  = lane & 15;
    const int quad = lane >> 4;

    const int n0  = blockIdx.x * 64;
    const int bz  = blockIdx.z;
    const int b   = bz >> 1, src = bz & 1;

    const float* xg = (src ? xs : xq) + (size_t)b * NCH * NPIX + n0;
    #pragma unroll
    for (int k0 = 0; k0 < 64; k0 += 16) {
        float v[16];
        #pragma unroll
        for (int k = 0; k < 16; ++k) {
            int idx = tid + (k0 + k) * 256;
            int c = idx >> 6, n = idx & 63;
            v[k] = xg[(size_t)c * NPIX + n];
        }
        #pragma unroll
        for (int k = 0; k < 16; ++k) {
            int idx = tid + (k0 + k) * 256;
            int c = idx >> 6, n = idx & 63;
            Xs[n * 264 + c] = f2bfu(v[k]);
        }
    }
    __syncthreads();

    const u16* W = Wbf + (size_t)src * 384 * 256;
    const int o0w = wid * 96;
    const float* bk = src ? b_k2 : b_k1;
    const float* bq = src ? b_q2 : b_q1;
    const float* bt = src ? b_ts : b_tq;

    f32x4 acc[24];
    #pragma unroll
    for (int ot = 0; ot < 6; ++ot) {
        int ob = o0w + ot * 16 + quad * 4;
        const float* bp;
        if (ob < 128)      bp = b_v + ob;
        else if (ob < 192) bp = bk + (ob - 128);
        else if (ob < 256) bp = bq + (ob - 192);
        else               bp = bt + (ob - 256);
        float4 b4 = *(const float4*)bp;
        f32x4 iv = (f32x4){b4.x, b4.y, b4.z, b4.w};
        #pragma unroll
        for (int pt = 0; pt < 4; ++pt) acc[ot * 4 + pt] = iv;
    }

    #pragma unroll
    for (int kc = 0; kc < 8; ++kc) {
        short8 bfr[4];
        #pragma unroll
        for (int pt = 0; pt < 4; ++pt)
            bfr[pt] = *(const short8*)&Xs[(pt * 16 + l16) * 264 + kc * 32 + quad * 8];
        #pragma unroll
        for (int ot = 0; ot < 6; ++ot) {
            short8 a = *(const short8*)&W[(size_t)(o0w + ot * 16 + l16) * 256 + kc * 32 + quad * 8];
            #pragma unroll
            for (int pt = 0; pt < 4; ++pt)
                acc[ot * 4 + pt] = __builtin_amdgcn_mfma_f32_16x16x32_bf16(a, bfr[pt], acc[ot * 4 + pt], 0, 0, 0);
        }
    }

    #pragma unroll
    for (int ot = 0; ot < 6; ++ot) {
        int ob = o0w + ot * 16;
        #pragma unroll
        for (int pt = 0; pt < 4; ++pt) {
            int px = pt * 16 + l16;
            f32x4 v4 = acc[ot * 4 + pt];
            if (ob < 128) {
                u16* dst = src ? vs : vq;
                #pragma unroll
                for (int r = 0; r < 4; ++r)
                    dst[((size_t)b * CI + ob + quad * 4 + r) * NPIX + n0 + px] = f2bfu(v4[r]);
            } else if (ob < 256) {
                int colb = (ob < 192) ? (ob - 128) : (64 + ob - 192);
                #pragma unroll
                for (int r = 0; r < 4; ++r)
                    KQ[px * 136 + colb + quad * 4 + r] = f2bfu(v4[r]);
            } else {
                const float* g  = src ? g_ts  : g_tq;
                const float* be = src ? be_ts : be_tq;
                const float* mm = src ? m_ts  : m_tq;
                const float* vv = src ? v_ts  : v_tq;
                u16* dst = src ? ts : tq;
                #pragma unroll
                for (int r = 0; r < 4; ++r) {
                    int oc = ob - 256 + quad * 4 + r;
                    float inv = g[oc] * rsqrtf(vv[oc] + EPS);
                    dst[((size_t)b * CI + oc) * NPIX + n0 + px] =
                        f2bfu((v4[r] - mm[oc]) * inv + be[oc]);
                }
            }
        }
    }
    __syncthreads();

    const int chb = src ? 64 : 0;
    #pragma unroll
    for (int u = 0; u < 4; ++u) {
        int idx = tid + u * 256;
        int px = idx >> 4, oct = idx & 15;
        uint4 val = *(const uint4*)&KQ[px * 136 + oct * 8];
        if (oct < 8)
            *(uint4*)&kT[((size_t)b * NPIX + n0 + px) * CI + chb + oct * 8] = val;
        else
            *(uint4*)&qT[((size_t)b * NPIX + n0 + px) * CI + chb + (oct - 8) * 8] = val;
    }
}

// =====================================================================
// Kernel 2: dual flash attention, split-m, async-DMA double buffer.
// R7 kernel BYTE-IDENTICAL (verified, 50.4 us @ nseg=4). 128-q blocks,
// two 16-row strips per wave, kf/bv shared. LDS 43008 B -> 3 blocks/CU.
// =====================================================================
#define AKS_OFF 0
#define AVT_OFF 8192
#define APS_OFF 16384
#define ASMEM_U16 21504   // 2*4096 (K dbuf) + 2*4096 (V dbuf) + 128*40 (Ps)

__global__ __launch_bounds__(256, 3) void attn_kernel(
    const u16* __restrict__ kT, const u16* __restrict__ qT,
    const u16* __restrict__ vq, const u16* __restrict__ vs,
    u16* __restrict__ Opart, float* __restrict__ Lpart, int nseg)
{
    __shared__ __align__(16) u16 smem[ASMEM_U16];
    u16* Ps = smem + APS_OFF;   // [q-row 128][m 32 + pad8] stride 40

    const int tid  = threadIdx.x;
    const int lane = tid & 63;
    const int wid  = tid >> 6;
    const int l16  = lane & 15;
    const int quad = lane >> 4;
    const int strip = wid * 16;

    const int ntb = blockIdx.x;       // 0..31 (128 q-rows per block)
    const int n0 = ntb * 128;
    const int at = blockIdx.y;
    const int z  = blockIdx.z;
    const int b  = z / nseg;
    const int seg = z - b * nseg;

    const u16* Qg = at ? qT : kT;
    const u16* Kg = at ? kT : qT;
    const u16* Vg = at ? vq : vs;

    // Q fragments for both strips (B-operand for S^T), held in regs
    short8 qf0[4], qf1[4];
    {
        const u16* Qb0 = Qg + ((size_t)b * NPIX + n0 + strip + l16) * CI;
        const u16* Qb1 = Qb0 + (size_t)64 * CI;
        #pragma unroll
        for (int kc = 0; kc < 4; ++kc) {
            qf0[kc] = *(const short8*)&Qb0[kc * 32 + quad * 8];
            qf1[kc] = *(const short8*)&Qb1[kc * 32 + quad * 8];
        }
    }

    f32x4 o0[8], o1[8];
    #pragma unroll
    for (int ct = 0; ct < 8; ++ct) {
        o0[ct] = (f32x4){0.f, 0.f, 0.f, 0.f};
        o1[ct] = (f32x4){0.f, 0.f, 0.f, 0.f};
    }
    float L0 = 0.f, L1 = 0.f;

    const u16* KgB = Kg + (size_t)b * NPIX * CI;
    const u16* VgB = Vg + (size_t)b * CI * NPIX;

    const int mt0 = seg * (128 / nseg);
    const int mt1 = mt0 + (128 / nseg);

    #define ISSUE_TILE(buf, m0_)                                              \
    {                                                                         \
        u16* kb_ = smem + AKS_OFF + (buf) * 4096;                             \
        u16* vb_ = smem + AVT_OFF + (buf) * 4096;                             \
        _Pragma("unroll")                                                     \
        for (int k = 0; k < 2; ++k) {                                         \
            int sb  = k * 256 + wid * 64;                                     \
            int idx = sb + lane;                                              \
            int row = idx >> 4, segp = idx & 15;                              \
            int segg = segp ^ (row & 15);                                     \
            gload16(KgB + (size_t)((m0_) + row) * CI + segg * 8, kb_ + sb * 8); \
        }                                                                     \
        _Pragma("unroll")                                                     \
        for (int k = 0; k < 2; ++k) {                                         \
            int sb  = k * 256 + wid * 64;                                     \
            int idx = sb + lane;                                              \
            int c = idx >> 2, sgp = idx & 3;                                  \
            int sgg = sgp ^ ((c >> 1) & 3);                                   \
            gload16(VgB + (size_t)c * NPIX + (m0_) + sgg * 8, vb_ + sb * 8);  \
        }                                                                     \
    }

    int cur = 0;
    ISSUE_TILE(0, mt0 * 32);

    for (int mt = mt0; mt < mt1; ++mt) {
        __syncthreads();   // vmcnt(0) drain: tile mt landed; prev buf free
        if (mt + 1 < mt1) ISSUE_TILE(1 - cur, (mt + 1) * 32);

        const u16* Ks = smem + AKS_OFF + cur * 4096;
        const u16* Vt = smem + AVT_OFF + cur * 4096;

        // ---- S^T = K Q^T : 2 m-tiles x 2 strips; kf shared ----
        f32x4 sv0[2], sv1[2];
        __builtin_amdgcn_s_setprio(1);
        #pragma unroll
        for (int m2 = 0; m2 < 2; ++m2) {
            f32x4 c0 = (f32x4){0.f, 0.f, 0.f, 0.f};
            f32x4 c1 = (f32x4){0.f, 0.f, 0.f, 0.f};
            #pragma unroll
            for (int kc = 0; kc < 4; ++kc) {
                int s = kc * 4 + quad;
                short8 kf = *(const short8*)&Ks[(m2 * 16 + l16) * 128 + ((s ^ l16) * 8)];
                c0 = __builtin_amdgcn_mfma_f32_16x16x32_bf16(kf, qf0[kc], c0, 0, 0, 0);
                c1 = __builtin_amdgcn_mfma_f32_16x16x32_bf16(kf, qf1[kc], c1, 0, 0, 0);
            }
            sv0[m2] = c0;
            sv1[m2] = c1;
        }
        __builtin_amdgcn_s_setprio(0);

        // ---- no-max softmax, both strips ----
        float Lsum0 = 0.f, Lsum1 = 0.f;
        u16* myPs0 = Ps + (strip + l16) * 40;
        u16* myPs1 = Ps + (64 + strip + l16) * 40;
        #pragma unroll
        for (int m2 = 0; m2 < 2; ++m2) {
            float p0 = __expf(sv0[m2][0] - SOFF);
            float p1 = __expf(sv0[m2][1] - SOFF);
            float p2 = __expf(sv0[m2][2] - SOFF);
            float p3 = __expf(sv0[m2][3] - SOFF);
            Lsum0 += (p0 + p1) + (p2 + p3);
            unsigned int r0, r1;
            asm("v_cvt_pk_bf16_f32 %0, %1, %2" : "=v"(r0) : "v"(p0), "v"(p1));
            asm("v_cvt_pk_bf16_f32 %0, %1, %2" : "=v"(r1) : "v"(p2), "v"(p3));
            uint2 pk; pk.x = r0; pk.y = r1;
            *(uint2*)&myPs0[m2 * 16 + quad * 4] = pk;

            float q0 = __expf(sv1[m2][0] - SOFF);
            float q1 = __expf(sv1[m2][1] - SOFF);
            float q2 = __expf(sv1[m2][2] - SOFF);
            float q3 = __expf(sv1[m2][3] - SOFF);
            Lsum1 += (q0 + q1) + (q2 + q3);
            unsigned int r2, r3;
            asm("v_cvt_pk_bf16_f32 %0, %1, %2" : "=v"(r2) : "v"(q0), "v"(q1));
            asm("v_cvt_pk_bf16_f32 %0, %1, %2" : "=v"(r3) : "v"(q2), "v"(q3));
            uint2 qk; qk.x = r2; qk.y = r3;
            *(uint2*)&myPs1[m2 * 16 + quad * 4] = qk;
        }
        Lsum0 += __shfl_xor(Lsum0, 16);
        Lsum0 += __shfl_xor(Lsum0, 32);
        L0 += Lsum0;
        Lsum1 += __shfl_xor(Lsum1, 16);
        Lsum1 += __shfl_xor(Lsum1, 32);
        L1 += Lsum1;

        // ---- PV both strips; bv shared (Ps rows intra-wave: no barrier) ----
        short8 ap0 = *(const short8*)&Ps[(strip + l16) * 40 + quad * 8];
        short8 ap1 = *(const short8*)&Ps[(64 + strip + l16) * 40 + quad * 8];
        __builtin_amdgcn_s_setprio(1);
        #pragma unroll
        for (int ct = 0; ct < 8; ++ct) {
            int cc = ct * 16 + l16;
            int fc = (cc >> 1) & 3;
            short8 bv = *(const short8*)&Vt[cc * 32 + ((quad ^ fc) * 8)];
            o0[ct] = __builtin_amdgcn_mfma_f32_16x16x32_bf16(ap0, bv, o0[ct], 0, 0, 0);
            o1[ct] = __builtin_amdgcn_mfma_f32_16x16x32_bf16(ap1, bv, o1[ct], 0, 0, 0);
        }
        __builtin_amdgcn_s_setprio(0);
        cur ^= 1;
    }

    // ---- store partials: two 64-row tiles (combine kernel unchanged) ----
    const size_t tile0 = (((size_t)(at * 2 + b) * 64 + 2 * ntb)     * nseg + seg);
    const size_t tile1 = (((size_t)(at * 2 + b) * 64 + 2 * ntb + 1) * nseg + seg);
    u16* Ob0 = Opart + tile0 * 8192;
    u16* Ob1 = Opart + tile1 * 8192;
    #pragma unroll
    for (int r = 0; r < 4; ++r) {
        int row = strip + quad * 4 + r;
        #pragma unroll
        for (int ct = 0; ct < 8; ++ct) {
            Ob0[row * 128 + ct * 16 + l16] = f2bfu(o0[ct][r]);
            Ob1[row * 128 + ct * 16 + l16] = f2bfu(o1[ct][r]);
        }
    }
    if (quad == 0) {
        Lpart[tile0 * 64 + strip + l16] = L0;
        Lpart[tile1 * 64 + strip + l16] = L1;
    }
    #undef ISSUE_TILE
}

// =====================================================================
// Kernel 2b: combine split-m partials (plain sum / sum-L) + epilogue.
// =====================================================================
__global__ __launch_bounds__(256) void attn_combine_kernel(
    const u16* __restrict__ Opart, const float* __restrict__ Lpart,
    const u16* __restrict__ tq, const u16* __restrict__ ts,
    const float* __restrict__ scale_p,
    float* __restrict__ out, u16* __restrict__ Ebf, int nseg)
{
    __shared__ float Of[128 * 68];
    __shared__ float invL[64];

    const int tid = threadIdx.x;
    const int nt = blockIdx.x;
    const int n0 = nt * 64;
    const int at = blockIdx.y;
    const int b  = blockIdx.z;

    const u16* Tg = at ? tq : ts;
    float* outE   = out + (size_t)(at ? 1 : 2) * 1048576;
    const int ch0 = at ? 0 : 128;
    const size_t tbase = ((size_t)(at * 2 + b) * 64 + nt) * nseg;

    if (tid < 64) {
        float Lg = 0.f;
        for (int s = 0; s < nseg; ++s) Lg += Lpart[(tbase + s) * 64 + tid];
        invL[tid] = 1.f / Lg;
    }
    __syncthreads();

    #pragma unroll
    for (int k = 0; k < 4; ++k) {
        int idx = tid + k * 256;
        int row = idx >> 4, oct = idx & 15;
        float m[8] = {0.f, 0.f, 0.f, 0.f, 0.f, 0.f, 0.f, 0.f};
        for (int s = 0; s < nseg; ++s) {
            union { uint4 v; u16 u[8]; } pk;
            pk.v = *(const uint4*)&Opart[(tbase + s) * 8192 + row * 128 + oct * 8];
            #pragma unroll
            for (int j = 0; j < 8; ++j) m[j] += bfu2f(pk.u[j]);
        }
        float w = invL[row];
        #pragma unroll
        for (int j = 0; j < 8; ++j)
            Of[(oct * 8 + j) * 68 + row] = m[j] * w;
    }
    __syncthreads();

    float scale = *scale_p;
    const u16* Tb = Tg + (size_t)b * CI * NPIX + n0;
    float* Ob = outE + (size_t)b * CI * NPIX + n0;
    for (int idx = tid; idx < 128 * 64; idx += 256) {
        int c = idx >> 6, r = idx & 63;
        float v = scale * Of[c * 68 + r] + bfu2f(Tb[(size_t)c * NPIX + r]);
        Ob[(size_t)c * NPIX + r] = v;
        Ebf[((size_t)b * NPIX + n0 + r) * NCH + ch0 + c] = f2bfu(v);
    }
}

// =====================================================================
// Kernel 3: 3x3 conv MFMA implicit GEMM.
// R11: grid restored to (64,4,2) = 512 blocks (R10's 1-block/CU merge
// regressed). Staging now SHARED per pxt-group: waves (cot=0,pg) and
// (cot=1,pg) stage identical slices in R7 -> one shared XtW[pg] staged
// cooperatively (stride 128, disjoint u coverage), with uniform
// stage->barrier->consume->barrier per icc. Staging global reads halve
// (107 -> 53.5 MB) at UNCHANGED parallelism. LDS 65 -> 16 KB.
// =====================================================================
#define CXT_STR 40

__global__ __launch_bounds__(256) void conv_kernel(
    const u16* __restrict__ Ebf,
    const u16* __restrict__ wT,
    const float* __restrict__ g_cat, const float* __restrict__ be_cat,
    const float* __restrict__ m_cat, const float* __restrict__ v_cat,
    float* __restrict__ out)
{
    __shared__ u16 XtW[2][3 * 34 * CXT_STR];   // shared per pxt-group

    const int tid  = threadIdx.x;
    const int lane = tid & 63;
    const int wid  = tid >> 6;
    const int l16  = lane & 15;
    const int quad = lane >> 4;

    const int h    = blockIdx.x;
    const int coff = blockIdx.y * 32;     // 0,32,64,96
    const int b    = blockIdx.z;

    const int cot = wid >> 1;             // co tile (16) within block
    const int pg  = wid & 1;              // pxt group (shares staged slice)
    const int pxt = pg * 2;               // px tiles {pxt, pxt+1}
    const int gc0 = pxt * 16 - 1;         // global col of local x=0

    f32x4 acc[2];
    #pragma unroll
    for (int j = 0; j < 2; ++j) acc[j] = (f32x4){0.f, 0.f, 0.f, 0.f};

    const u16* Eb = Ebf + (size_t)b * NPIX * NCH;
    u16* Xw = &XtW[pg][0];
    const int cobase = coff + cot * 16 + l16;

    for (int icc = 0; icc < 8; ++icc) {
        const int ic0 = icc * 32;

        // weight fragments (L2-resident, independent loads)
        short8 wfrag[9];
        #pragma unroll
        for (int tap = 0; tap < 9; ++tap)
            wfrag[tap] = *(const short8*)&wT[((size_t)cobase * 9 + tap) * 256 + ic0 + quad * 8];

        // cooperative staging: pair (cot=0,pg) + (cot=1,pg), stride 128
        for (int u = cot * 64 + lane; u < 408; u += 128) {
            int part = u & 3, xe = u >> 2;       // xe 0..101
            int dh = xe / 34, x = xe - dh * 34;  // x 0..33
            int gr = h + dh - 1, gc = gc0 + x;
            uint4 val = make_uint4(0u, 0u, 0u, 0u);
            if ((unsigned)gr < 64u && (unsigned)gc < 64u)
                val = *(const uint4*)&Eb[((size_t)gr * 64 + gc) * NCH + ic0 + part * 8];
            *(uint4*)&Xw[(dh * 34 + x) * CXT_STR + part * 8] = val;
        }
        __syncthreads();   // pair's staged slice complete

        #pragma unroll
        for (int tap = 0; tap < 9; ++tap) {
            const int dh = tap / 3, dw = tap % 3;
            short8 bf[2];
            #pragma unroll
            for (int j = 0; j < 2; ++j) {
                int x = j * 16 + l16 + dw;        // local col 0..33
                bf[j] = *(const short8*)&Xw[(dh * 34 + x) * CXT_STR + quad * 8];
            }
            #pragma unroll
            for (int j = 0; j < 2; ++j)
                acc[j] = __builtin_amdgcn_mfma_f32_16x16x32_bf16(wfrag[tap], bf[j], acc[j], 0, 0, 0);
        }
        __syncthreads();   // all reads done before next icc overwrite
    }

    #pragma unroll
    for (int r = 0; r < 4; ++r) {
        int co = coff + cot * 16 + quad * 4 + r;
        float inv = g_cat[co] * rsqrtf(v_cat[co] + EPS);
        float mm  = m_cat[co];
        float be  = be_cat[co];
        #pragma unroll
        for (int j = 0; j < 2; ++j) {
            int wcol = (pxt + j) * 16 + l16;
            float v = (acc[j][r] - mm) * inv + be;
            out[((size_t)b * CI + co) * NPIX + h * 64 + wcol] = fmaxf(v, 0.f);
        }
    }
}

// =====================================================================
extern "C" void kernel_launch(void* const* d_in, const int* in_sizes, int n_in,
                              void* d_out, int out_size, void* d_ws, size_t ws_size,
                              hipStream_t stream)
{
    const float* q     = (const float*)d_in[0];
    const float* s     = (const float*)d_in[1];
    const float* scale = (const float*)d_in[2];
    const float* w_v   = (const float*)d_in[3];
    const float* b_v   = (const float*)d_in[4];
    const float* w_k1  = (const float*)d_in[5];
    const float* b_k1  = (const float*)d_in[6];
    const float* w_q1  = (const float*)d_in[7];
    const float* b_q1  = (const float*)d_in[8];
    const float* w_k2  = (const float*)d_in[9];
    const float* b_k2  = (const float*)d_in[10];
    const float* w_q2  = (const float*)d_in[11];
    const float* b_q2  = (const float*)d_in[12];
    const float* w_ts  = (const float*)d_in[13];
    const float* b_ts  = (const float*)d_in[14];
    const float* g_ts  = (const float*)d_in[15];
    const float* be_ts = (const float*)d_in[16];
    const float* m_ts  = (const float*)d_in[17];
    const float* v_ts  = (const float*)d_in[18];
    const float* w_tq  = (const float*)d_in[19];
    const float* b_tq  = (const float*)d_in[20];
    const float* g_tq  = (const float*)d_in[21];
    const float* be_tq = (const float*)d_in[22];
    const float* m_tq  = (const float*)d_in[23];
    const float* v_tq  = (const float*)d_in[24];
    const float* w_cat = (const float*)d_in[25];
    const float* g_cat = (const float*)d_in[26];
    const float* be_cat= (const float*)d_in[27];
    const float* m_cat = (const float*)d_in[28];
    const float* v_cat = (const float*)d_in[29];

    float* out = (float*)d_out;
    u16* ws = (u16*)d_ws;
    const size_t SZ = (size_t)2 * CI * NPIX;        // 1,048,576 u16 per buffer
    u16* kT  = ws;
    u16* qT  = kT + SZ;
    u16* vq  = qT + SZ;
    u16* vs  = vq + SZ;
    u16* tq  = vs + SZ;
    u16* ts  = tq + SZ;
    u16* Wbf = ts + SZ;
    u16* B   = Wbf + 196608;
    u16* Ebf = B;
    u16* wTc = B + 2097152;
    u16* Opart = wTc + 294912;

    const size_t fixed_u16 = 6 * SZ + 196608 + 2097152 + 294912;
    int nseg = 1;
    {
        size_t need4 = (fixed_u16 + (size_t)4 * 2097152) * 2 + (size_t)4 * 131072;
        size_t need2 = (fixed_u16 + (size_t)2 * 2097152) * 2 + (size_t)2 * 131072;
        if (ws_size >= need4)      nseg = 4;
        else if (ws_size >= need2) nseg = 2;
    }
    float* Lpart = (float*)(Opart + (size_t)nseg * 256 * 8192);

    dim3 blk(256);
    hipLaunchKernelGGL(prep_kernel, dim3(896), blk, 0, stream,
                       w_v, w_k1, w_q1, w_k2, w_q2, w_ts, w_tq, Wbf, w_cat, wTc);
    hipLaunchKernelGGL(proj2_kernel, dim3(64, 1, 4), blk, 0, stream,
                       q, s, Wbf, b_v, b_k1, b_q1, b_k2, b_q2,
                       b_ts, g_ts, be_ts, m_ts, v_ts,
                       b_tq, g_tq, be_tq, m_tq, v_tq,
                       kT, qT, vq, vs, tq, ts);
    hipLaunchKernelGGL(attn_kernel, dim3(32, 2, 2 * nseg), blk, 0, stream,
                       kT, qT, vq, vs, Opart, Lpart, nseg);
    hipLaunchKernelGGL(attn_combine_kernel, dim3(64, 2, 2), blk, 0, stream,
                       Opart, Lpart, tq, ts, scale, out, Ebf, nseg);
    hipLaunchKernelGGL(conv_kernel, dim3(64, 4, 2), blk, 0, stream,
                       Ebf, wTc, g_cat, be_cat, m_cat, v_cat, out);
}

// Round 12
// 229.624 us; speedup vs baseline: 1.0563x; 1.0179x over previous
//
#include <hip/hip_runtime.h>
#include <hip/hip_bf16.h>

#define NPIX 4096   // H*W
#define NCH  256    // input channels
#define CI   128    // inter channels
#define EPS  1e-5f
#define SOFF 20.0f  // fixed softmax offset (cancels in normalization)

typedef unsigned short u16;
typedef __attribute__((ext_vector_type(8))) short short8;   // 8 bf16 (4 VGPRs)
typedef __attribute__((ext_vector_type(4))) float f32x4;    // MFMA C/D

// ---------- bf16 bit helpers ----------
__device__ __forceinline__ float bfu2f(u16 u) {
    union { unsigned int i; float f; } x; x.i = ((unsigned int)u) << 16; return x.f;
}
__device__ __forceinline__ u16 f2bfu(float f) {
    union { float ff; unsigned int i; } x; x.ff = f;
    unsigned int r = x.i + 0x7FFFu + ((x.i >> 16) & 1u);
    return (u16)(r >> 16);
}

// async global->LDS DMA, 16B per lane; dest = wave-uniform base + lane*16
__device__ __forceinline__ void gload16(const u16* g, u16* l) {
    __builtin_amdgcn_global_load_lds(
        (const __attribute__((address_space(1))) unsigned int*)g,
        (__attribute__((address_space(3))) unsigned int*)l,
        16, 0, 0);
}

// =====================================================================
// Kernel 0: merged weight prep.
// =====================================================================
__global__ __launch_bounds__(256) void prep_kernel(
    const float* __restrict__ w_v,
    const float* __restrict__ w_k1, const float* __restrict__ w_q1,
    const float* __restrict__ w_k2, const float* __restrict__ w_q2,
    const float* __restrict__ w_ts, const float* __restrict__ w_tq,
    u16* __restrict__ Wbf,
    const float* __restrict__ w_cat, u16* __restrict__ wT)
{
    const int bx = blockIdx.x;
    if (bx < 768) {
        int idx = bx * 256 + threadIdx.x;
        int src = idx / 98304;
        int r   = idx - src * 98304;
        int o   = r >> 8, c = r & 255;
        float v;
        if (o < 128)      v = w_v[(size_t)o * 256 + c];
        else if (o < 192) v = (src ? w_k2 : w_k1)[(size_t)(o - 128) * 256 + c];
        else if (o < 256) v = (src ? w_q2 : w_q1)[(size_t)(o - 192) * 256 + c];
        else              v = (src ? w_ts : w_tq)[(size_t)(o - 256) * 256 + c];
        Wbf[idx] = f2bfu(v);
    } else {
        int co = bx - 768;
        const float* srcb = w_cat + (size_t)co * 2304;
        u16* dstb = wT + (size_t)co * 2304;
        for (int t = threadIdx.x; t < 2304; t += 256) {
            int ic = t / 9, tap = t - ic * 9;
            dstb[tap * 256 + ic] = f2bfu(srcb[t]);
        }
    }
}

// =====================================================================
// Kernel 1: MFMA proj GEMM; stages fp32 q/s directly (unchanged).
// =====================================================================
__global__ __launch_bounds__(256) void proj2_kernel(
    const float* __restrict__ xq, const float* __restrict__ xs,
    const u16* __restrict__ Wbf,
    const float* __restrict__ b_v,
    const float* __restrict__ b_k1, const float* __restrict__ b_q1,
    const float* __restrict__ b_k2, const float* __restrict__ b_q2,
    const float* __restrict__ b_ts, const float* __restrict__ g_ts,
    const float* __restrict__ be_ts, const float* __restrict__ m_ts,
    const float* __restrict__ v_ts,
    const float* __restrict__ b_tq, const float* __restrict__ g_tq,
    const float* __restrict__ be_tq, const float* __restrict__ m_tq,
    const float* __restrict__ v_tq,
    u16* __restrict__ kT, u16* __restrict__ qT,
    u16* __restrict__ vq, u16* __restrict__ vs,
    u16* __restrict__ tq, u16* __restrict__ ts)
{
    __shared__ u16 Xs[64 * 264];
    __shared__ u16 KQ[64 * 136];

    const int tid  = threadIdx.x;
    const int lane = tid & 63;
    const int wid  = tid >> 6;
    const int l16  = lane & 15;
    const int quad = lane >> 4;

    const int n0  = blockIdx.x * 64;
    const int bz  = blockIdx.z;
    const int b   = bz >> 1, src = bz & 1;

    const float* xg = (src ? xs : xq) + (size_t)b * NCH * NPIX + n0;
    #pragma unroll
    for (int k0 = 0; k0 < 64; k0 += 16) {
        float v[16];
        #pragma unroll
        for (int k = 0; k < 16; ++k) {
            int idx = tid + (k0 + k) * 256;
            int c = idx >> 6, n = idx & 63;
            v[k] = xg[(size_t)c * NPIX + n];
        }
        #pragma unroll
        for (int k = 0; k < 16; ++k) {
            int idx = tid + (k0 + k) * 256;
            int c = idx >> 6, n = idx & 63;
            Xs[n * 264 + c] = f2bfu(v[k]);
        }
    }
    __syncthreads();

    const u16* W = Wbf + (size_t)src * 384 * 256;
    const int o0w = wid * 96;
    const float* bk = src ? b_k2 : b_k1;
    const float* bq = src ? b_q2 : b_q1;
    const float* bt = src ? b_ts : b_tq;

    f32x4 acc[24];
    #pragma unroll
    for (int ot = 0; ot < 6; ++ot) {
        int ob = o0w + ot * 16 + quad * 4;
        const float* bp;
        if (ob < 128)      bp = b_v + ob;
        else if (ob < 192) bp = bk + (ob - 128);
        else if (ob < 256) bp = bq + (ob - 192);
        else               bp = bt + (ob - 256);
        float4 b4 = *(const float4*)bp;
        f32x4 iv = (f32x4){b4.x, b4.y, b4.z, b4.w};
        #pragma unroll
        for (int pt = 0; pt < 4; ++pt) acc[ot * 4 + pt] = iv;
    }

    #pragma unroll
    for (int kc = 0; kc < 8; ++kc) {
        short8 bfr[4];
        #pragma unroll
        for (int pt = 0; pt < 4; ++pt)
            bfr[pt] = *(const short8*)&Xs[(pt * 16 + l16) * 264 + kc * 32 + quad * 8];
        #pragma unroll
        for (int ot = 0; ot < 6; ++ot) {
            short8 a = *(const short8*)&W[(size_t)(o0w + ot * 16 + l16) * 256 + kc * 32 + quad * 8];
            #pragma unroll
            for (int pt = 0; pt < 4; ++pt)
                acc[ot * 4 + pt] = __builtin_amdgcn_mfma_f32_16x16x32_bf16(a, bfr[pt], acc[ot * 4 + pt], 0, 0, 0);
        }
    }

    #pragma unroll
    for (int ot = 0; ot < 6; ++ot) {
        int ob = o0w + ot * 16;
        #pragma unroll
        for (int pt = 0; pt < 4; ++pt) {
            int px = pt * 16 + l16;
            f32x4 v4 = acc[ot * 4 + pt];
            if (ob < 128) {
                u16* dst = src ? vs : vq;
                #pragma unroll
                for (int r = 0; r < 4; ++r)
                    dst[((size_t)b * CI + ob + quad * 4 + r) * NPIX + n0 + px] = f2bfu(v4[r]);
            } else if (ob < 256) {
                int colb = (ob < 192) ? (ob - 128) : (64 + ob - 192);
                #pragma unroll
                for (int r = 0; r < 4; ++r)
                    KQ[px * 136 + colb + quad * 4 + r] = f2bfu(v4[r]);
            } else {
                const float* g  = src ? g_ts  : g_tq;
                const float* be = src ? be_ts : be_tq;
                const float* mm = src ? m_ts  : m_tq;
                const float* vv = src ? v_ts  : v_tq;
                u16* dst = src ? ts : tq;
                #pragma unroll
                for (int r = 0; r < 4; ++r) {
                    int oc = ob - 256 + quad * 4 + r;
                    float inv = g[oc] * rsqrtf(vv[oc] + EPS);
                    dst[((size_t)b * CI + oc) * NPIX + n0 + px] =
                        f2bfu((v4[r] - mm[oc]) * inv + be[oc]);
                }
            }
        }
    }
    __syncthreads();

    const int chb = src ? 64 : 0;
    #pragma unroll
    for (int u = 0; u < 4; ++u) {
        int idx = tid + u * 256;
        int px = idx >> 4, oct = idx & 15;
        uint4 val = *(const uint4*)&KQ[px * 136 + oct * 8];
        if (oct < 8)
            *(uint4*)&kT[((size_t)b * NPIX + n0 + px) * CI + chb + oct * 8] = val;
        else
            *(uint4*)&qT[((size_t)b * NPIX + n0 + px) * CI + chb + (oct - 8) * 8] = val;
    }
}

// =====================================================================
// Kernel 2: dual flash attention, split-m, async-DMA double buffer.
// R12 = R7 template (verified best) + deferred L reduction: the per-
// iteration quad-butterfly (4 shfl_xor/iter) is replaced by lane-local
// accumulation with ONE butterfly after the loop (identical result
// modulo FP order). 128-q blocks, two strips/wave, kf/bv shared.
// LDS 43008 B -> 3 blocks/CU.
// =====================================================================
#define AKS_OFF 0
#define AVT_OFF 8192
#define APS_OFF 16384
#define ASMEM_U16 21504   // 2*4096 (K dbuf) + 2*4096 (V dbuf) + 128*40 (Ps)

__global__ __launch_bounds__(256, 3) void attn_kernel(
    const u16* __restrict__ kT, const u16* __restrict__ qT,
    const u16* __restrict__ vq, const u16* __restrict__ vs,
    u16* __restrict__ Opart, float* __restrict__ Lpart, int nseg)
{
    __shared__ __align__(16) u16 smem[ASMEM_U16];
    u16* Ps = smem + APS_OFF;   // [q-row 128][m 32 + pad8] stride 40

    const int tid  = threadIdx.x;
    const int lane = tid & 63;
    const int wid  = tid >> 6;
    const int l16  = lane & 15;
    const int quad = lane >> 4;
    const int strip = wid * 16;

    const int ntb = blockIdx.x;       // 0..31 (128 q-rows per block)
    const int n0 = ntb * 128;
    const int at = blockIdx.y;
    const int z  = blockIdx.z;
    const int b  = z / nseg;
    const int seg = z - b * nseg;

    const u16* Qg = at ? qT : kT;
    const u16* Kg = at ? kT : qT;
    const u16* Vg = at ? vq : vs;

    // Q fragments for both strips (B-operand for S^T), held in regs
    short8 qf0[4], qf1[4];
    {
        const u16* Qb0 = Qg + ((size_t)b * NPIX + n0 + strip + l16) * CI;
        const u16* Qb1 = Qb0 + (size_t)64 * CI;
        #pragma unroll
        for (int kc = 0; kc < 4; ++kc) {
            qf0[kc] = *(const short8*)&Qb0[kc * 32 + quad * 8];
            qf1[kc] = *(const short8*)&Qb1[kc * 32 + quad * 8];
        }
    }

    f32x4 o0[8], o1[8];
    #pragma unroll
    for (int ct = 0; ct < 8; ++ct) {
        o0[ct] = (f32x4){0.f, 0.f, 0.f, 0.f};
        o1[ct] = (f32x4){0.f, 0.f, 0.f, 0.f};
    }
    float L0 = 0.f, L1 = 0.f;   // lane-local partials; reduced after loop

    const u16* KgB = Kg + (size_t)b * NPIX * CI;
    const u16* VgB = Vg + (size_t)b * CI * NPIX;

    const int mt0 = seg * (128 / nseg);
    const int mt1 = mt0 + (128 / nseg);

    #define ISSUE_TILE(buf, m0_)                                              \
    {                                                                         \
        u16* kb_ = smem + AKS_OFF + (buf) * 4096;                             \
        u16* vb_ = smem + AVT_OFF + (buf) * 4096;                             \
        _Pragma("unroll")                                                     \
        for (int k = 0; k < 2; ++k) {                                         \
            int sb  = k * 256 + wid * 64;                                     \
            int idx = sb + lane;                                              \
            int row = idx >> 4, segp = idx & 15;                              \
            int segg = segp ^ (row & 15);                                     \
            gload16(KgB + (size_t)((m0_) + row) * CI + segg * 8, kb_ + sb * 8); \
        }                                                                     \
        _Pragma("unroll")                                                     \
        for (int k = 0; k < 2; ++k) {                                         \
            int sb  = k * 256 + wid * 64;                                     \
            int idx = sb + lane;                                              \
            int c = idx >> 2, sgp = idx & 3;                                  \
            int sgg = sgp ^ ((c >> 1) & 3);                                   \
            gload16(VgB + (size_t)c * NPIX + (m0_) + sgg * 8, vb_ + sb * 8);  \
        }                                                                     \
    }

    int cur = 0;
    ISSUE_TILE(0, mt0 * 32);

    for (int mt = mt0; mt < mt1; ++mt) {
        __syncthreads();   // vmcnt(0) drain: tile mt landed; prev buf free
        if (mt + 1 < mt1) ISSUE_TILE(1 - cur, (mt + 1) * 32);

        const u16* Ks = smem + AKS_OFF + cur * 4096;
        const u16* Vt = smem + AVT_OFF + cur * 4096;

        // ---- S^T = K Q^T : 2 m-tiles x 2 strips; kf shared ----
        f32x4 sv0[2], sv1[2];
        __builtin_amdgcn_s_setprio(1);
        #pragma unroll
        for (int m2 = 0; m2 < 2; ++m2) {
            f32x4 c0 = (f32x4){0.f, 0.f, 0.f, 0.f};
            f32x4 c1 = (f32x4){0.f, 0.f, 0.f, 0.f};
            #pragma unroll
            for (int kc = 0; kc < 4; ++kc) {
                int s = kc * 4 + quad;
                short8 kf = *(const short8*)&Ks[(m2 * 16 + l16) * 128 + ((s ^ l16) * 8)];
                c0 = __builtin_amdgcn_mfma_f32_16x16x32_bf16(kf, qf0[kc], c0, 0, 0, 0);
                c1 = __builtin_amdgcn_mfma_f32_16x16x32_bf16(kf, qf1[kc], c1, 0, 0, 0);
            }
            sv0[m2] = c0;
            sv1[m2] = c1;
        }
        __builtin_amdgcn_s_setprio(0);

        // ---- no-max softmax, both strips; L kept lane-local ----
        u16* myPs0 = Ps + (strip + l16) * 40;
        u16* myPs1 = Ps + (64 + strip + l16) * 40;
        #pragma unroll
        for (int m2 = 0; m2 < 2; ++m2) {
            float p0 = __expf(sv0[m2][0] - SOFF);
            float p1 = __expf(sv0[m2][1] - SOFF);
            float p2 = __expf(sv0[m2][2] - SOFF);
            float p3 = __expf(sv0[m2][3] - SOFF);
            L0 += (p0 + p1) + (p2 + p3);
            unsigned int r0, r1;
            asm("v_cvt_pk_bf16_f32 %0, %1, %2" : "=v"(r0) : "v"(p0), "v"(p1));
            asm("v_cvt_pk_bf16_f32 %0, %1, %2" : "=v"(r1) : "v"(p2), "v"(p3));
            uint2 pk; pk.x = r0; pk.y = r1;
            *(uint2*)&myPs0[m2 * 16 + quad * 4] = pk;

            float q0 = __expf(sv1[m2][0] - SOFF);
            float q1 = __expf(sv1[m2][1] - SOFF);
            float q2 = __expf(sv1[m2][2] - SOFF);
            float q3 = __expf(sv1[m2][3] - SOFF);
            L1 += (q0 + q1) + (q2 + q3);
            unsigned int r2, r3;
            asm("v_cvt_pk_bf16_f32 %0, %1, %2" : "=v"(r2) : "v"(q0), "v"(q1));
            asm("v_cvt_pk_bf16_f32 %0, %1, %2" : "=v"(r3) : "v"(q2), "v"(q3));
            uint2 qk; qk.x = r2; qk.y = r3;
            *(uint2*)&myPs1[m2 * 16 + quad * 4] = qk;
        }

        // ---- PV both strips; bv shared (Ps rows intra-wave: no barrier) ----
        short8 ap0 = *(const short8*)&Ps[(strip + l16) * 40 + quad * 8];
        short8 ap1 = *(const short8*)&Ps[(64 + strip + l16) * 40 + quad * 8];
        __builtin_amdgcn_s_setprio(1);
        #pragma unroll
        for (int ct = 0; ct < 8; ++ct) {
            int cc = ct * 16 + l16;
            int fc = (cc >> 1) & 3;
            short8 bv = *(const short8*)&Vt[cc * 32 + ((quad ^ fc) * 8)];
            o0[ct] = __builtin_amdgcn_mfma_f32_16x16x32_bf16(ap0, bv, o0[ct], 0, 0, 0);
            o1[ct] = __builtin_amdgcn_mfma_f32_16x16x32_bf16(ap1, bv, o1[ct], 0, 0, 0);
        }
        __builtin_amdgcn_s_setprio(0);
        cur ^= 1;
    }

    // ---- deferred L reduction: one quad-butterfly per strip ----
    L0 += __shfl_xor(L0, 16);
    L0 += __shfl_xor(L0, 32);
    L1 += __shfl_xor(L1, 16);
    L1 += __shfl_xor(L1, 32);

    // ---- store partials: two 64-row tiles (combine kernel unchanged) ----
    const size_t tile0 = (((size_t)(at * 2 + b) * 64 + 2 * ntb)     * nseg + seg);
    const size_t tile1 = (((size_t)(at * 2 + b) * 64 + 2 * ntb + 1) * nseg + seg);
    u16* Ob0 = Opart + tile0 * 8192;
    u16* Ob1 = Opart + tile1 * 8192;
    #pragma unroll
    for (int r = 0; r < 4; ++r) {
        int row = strip + quad * 4 + r;
        #pragma unroll
        for (int ct = 0; ct < 8; ++ct) {
            Ob0[row * 128 + ct * 16 + l16] = f2bfu(o0[ct][r]);
            Ob1[row * 128 + ct * 16 + l16] = f2bfu(o1[ct][r]);
        }
    }
    if (quad == 0) {
        Lpart[tile0 * 64 + strip + l16] = L0;
        Lpart[tile1 * 64 + strip + l16] = L1;
    }
    #undef ISSUE_TILE
}

// =====================================================================
// Kernel 2b: combine split-m partials (plain sum / sum-L) + epilogue.
// =====================================================================
__global__ __launch_bounds__(256) void attn_combine_kernel(
    const u16* __restrict__ Opart, const float* __restrict__ Lpart,
    const u16* __restrict__ tq, const u16* __restrict__ ts,
    const float* __restrict__ scale_p,
    float* __restrict__ out, u16* __restrict__ Ebf, int nseg)
{
    __shared__ float Of[128 * 68];
    __shared__ float invL[64];

    const int tid = threadIdx.x;
    const int nt = blockIdx.x;
    const int n0 = nt * 64;
    const int at = blockIdx.y;
    const int b  = blockIdx.z;

    const u16* Tg = at ? tq : ts;
    float* outE   = out + (size_t)(at ? 1 : 2) * 1048576;
    const int ch0 = at ? 0 : 128;
    const size_t tbase = ((size_t)(at * 2 + b) * 64 + nt) * nseg;

    if (tid < 64) {
        float Lg = 0.f;
        for (int s = 0; s < nseg; ++s) Lg += Lpart[(tbase + s) * 64 + tid];
        invL[tid] = 1.f / Lg;
    }
    __syncthreads();

    #pragma unroll
    for (int k = 0; k < 4; ++k) {
        int idx = tid + k * 256;
        int row = idx >> 4, oct = idx & 15;
        float m[8] = {0.f, 0.f, 0.f, 0.f, 0.f, 0.f, 0.f, 0.f};
        for (int s = 0; s < nseg; ++s) {
            union { uint4 v; u16 u[8]; } pk;
            pk.v = *(const uint4*)&Opart[(tbase + s) * 8192 + row * 128 + oct * 8];
            #pragma unroll
            for (int j = 0; j < 8; ++j) m[j] += bfu2f(pk.u[j]);
        }
        float w = invL[row];
        #pragma unroll
        for (int j = 0; j < 8; ++j)
            Of[(oct * 8 + j) * 68 + row] = m[j] * w;
    }
    __syncthreads();

    float scale = *scale_p;
    const u16* Tb = Tg + (size_t)b * CI * NPIX + n0;
    float* Ob = outE + (size_t)b * CI * NPIX + n0;
    for (int idx = tid; idx < 128 * 64; idx += 256) {
        int c = idx >> 6, r = idx & 63;
        float v = scale * Of[c * 68 + r] + bfu2f(Tb[(size_t)c * NPIX + r]);
        Ob[(size_t)c * NPIX + r] = v;
        Ebf[((size_t)b * NPIX + n0 + r) * NCH + ch0 + c] = f2bfu(v);
    }
}

// =====================================================================
// Kernel 3: 3x3 conv MFMA implicit GEMM, BARRIER-FREE: each wave stages
// its own 3x34-halo x 32ic slice into a private LDS region (R7 verified
// version; R10/R11 traffic reductions were neutral-to-negative).
// =====================================================================
#define CXT_STR 40

__global__ __launch_bounds__(256) void conv_kernel(
    const u16* __restrict__ Ebf,
    const u16* __restrict__ wT,
    const float* __restrict__ g_cat, const float* __restrict__ be_cat,
    const float* __restrict__ m_cat, const float* __restrict__ v_cat,
    float* __restrict__ out)
{
    __shared__ u16 XtW[4][3 * 34 * CXT_STR];   // per-wave private slices

    const int tid  = threadIdx.x;
    const int lane = tid & 63;
    const int wid  = tid >> 6;
    const int l16  = lane & 15;
    const int quad = lane >> 4;

    const int h    = blockIdx.x;
    const int coff = blockIdx.y * 32;     // 0,32,64,96
    const int b    = blockIdx.z;

    const int cot = wid >> 1;             // co tile (16) within block
    const int pxt = (wid & 1) * 2;        // px tiles {pxt, pxt+1}
    const int gc0 = pxt * 16 - 1;         // global col of local x=0

    f32x4 acc[2];
    #pragma unroll
    for (int j = 0; j < 2; ++j) acc[j] = (f32x4){0.f, 0.f, 0.f, 0.f};

    const u16* Eb = Ebf + (size_t)b * NPIX * NCH;
    u16* Xw = &XtW[wid][0];
    const int cobase = coff + cot * 16 + l16;

    for (int icc = 0; icc < 8; ++icc) {
        const int ic0 = icc * 32;

        // weight fragments (L2-resident, independent loads)
        short8 wfrag[9];
        #pragma unroll
        for (int tap = 0; tap < 9; ++tap)
            wfrag[tap] = *(const short8*)&wT[((size_t)cobase * 9 + tap) * 256 + ic0 + quad * 8];

        // private staging: 3 rows x 34 cols x 4 parts = 408 uint4 per wave
        for (int u = lane; u < 408; u += 64) {
            int part = u & 3, xe = u >> 2;       // xe 0..101
            int dh = xe / 34, x = xe - dh * 34;  // x 0..33
            int gr = h + dh - 1, gc = gc0 + x;
            uint4 val = make_uint4(0u, 0u, 0u, 0u);
            if ((unsigned)gr < 64u && (unsigned)gc < 64u)
                val = *(const uint4*)&Eb[((size_t)gr * 64 + gc) * NCH + ic0 + part * 8];
            *(uint4*)&Xw[(dh * 34 + x) * CXT_STR + part * 8] = val;
        }

        #pragma unroll
        for (int tap = 0; tap < 9; ++tap) {
            const int dh = tap / 3, dw = tap % 3;
            short8 bf[2];
            #pragma unroll
            for (int j = 0; j < 2; ++j) {
                int x = j * 16 + l16 + dw;        // local col 0..33
                bf[j] = *(const short8*)&Xw[(dh * 34 + x) * CXT_STR + quad * 8];
            }
            #pragma unroll
            for (int j = 0; j < 2; ++j)
                acc[j] = __builtin_amdgcn_mfma_f32_16x16x32_bf16(wfrag[tap], bf[j], acc[j], 0, 0, 0);
        }
    }

    #pragma unroll
    for (int r = 0; r < 4; ++r) {
        int co = coff + cot * 16 + quad * 4 + r;
        float inv = g_cat[co] * rsqrtf(v_cat[co] + EPS);
        float mm  = m_cat[co];
        float be  = be_cat[co];
        #pragma unroll
        for (int j = 0; j < 2; ++j) {
            int wcol = (pxt + j) * 16 + l16;
            float v = (acc[j][r] - mm) * inv + be;
            out[((size_t)b * CI + co) * NPIX + h * 64 + wcol] = fmaxf(v, 0.f);
        }
    }
}

// =====================================================================
extern "C" void kernel_launch(void* const* d_in, const int* in_sizes, int n_in,
                              void* d_out, int out_size, void* d_ws, size_t ws_size,
                              hipStream_t stream)
{
    const float* q     = (const float*)d_in[0];
    const float* s     = (const float*)d_in[1];
    const float* scale = (const float*)d_in[2];
    const float* w_v   = (const float*)d_in[3];
    const float* b_v   = (const float*)d_in[4];
    const float* w_k1  = (const float*)d_in[5];
    const float* b_k1  = (const float*)d_in[6];
    const float* w_q1  = (const float*)d_in[7];
    const float* b_q1  = (const float*)d_in[8];
    const float* w_k2  = (const float*)d_in[9];
    const float* b_k2  = (const float*)d_in[10];
    const float* w_q2  = (const float*)d_in[11];
    const float* b_q2  = (const float*)d_in[12];
    const float* w_ts  = (const float*)d_in[13];
    const float* b_ts  = (const float*)d_in[14];
    const float* g_ts  = (const float*)d_in[15];
    const float* be_ts = (const float*)d_in[16];
    const float* m_ts  = (const float*)d_in[17];
    const float* v_ts  = (const float*)d_in[18];
    const float* w_tq  = (const float*)d_in[19];
    const float* b_tq  = (const float*)d_in[20];
    const float* g_tq  = (const float*)d_in[21];
    const float* be_tq = (const float*)d_in[22];
    const float* m_tq  = (const float*)d_in[23];
    const float* v_tq  = (const float*)d_in[24];
    const float* w_cat = (const float*)d_in[25];
    const float* g_cat = (const float*)d_in[26];
    const float* be_cat= (const float*)d_in[27];
    const float* m_cat = (const float*)d_in[28];
    const float* v_cat = (const float*)d_in[29];

    float* out = (float*)d_out;
    u16* ws = (u16*)d_ws;
    const size_t SZ = (size_t)2 * CI * NPIX;        // 1,048,576 u16 per buffer
    u16* kT  = ws;
    u16* qT  = kT + SZ;
    u16* vq  = qT + SZ;
    u16* vs  = vq + SZ;
    u16* tq  = vs + SZ;
    u16* ts  = tq + SZ;
    u16* Wbf = ts + SZ;
    u16* B   = Wbf + 196608;
    u16* Ebf = B;
    u16* wTc = B + 2097152;
    u16* Opart = wTc + 294912;

    const size_t fixed_u16 = 6 * SZ + 196608 + 2097152 + 294912;
    int nseg = 1;
    {
        size_t need4 = (fixed_u16 + (size_t)4 * 2097152) * 2 + (size_t)4 * 131072;
        size_t need2 = (fixed_u16 + (size_t)2 * 2097152) * 2 + (size_t)2 * 131072;
        if (ws_size >= need4)      nseg = 4;
        else if (ws_size >= need2) nseg = 2;
    }
    float* Lpart = (float*)(Opart + (size_t)nseg * 256 * 8192);

    dim3 blk(256);
    hipLaunchKernelGGL(prep_kernel, dim3(896), blk, 0, stream,
                       w_v, w_k1, w_q1, w_k2, w_q2, w_ts, w_tq, Wbf, w_cat, wTc);
    hipLaunchKernelGGL(proj2_kernel, dim3(64, 1, 4), blk, 0, stream,
                       q, s, Wbf, b_v, b_k1, b_q1, b_k2, b_q2,
                       b_ts, g_ts, be_ts, m_ts, v_ts,
                       b_tq, g_tq, be_tq, m_tq, v_tq,
                       kT, qT, vq, vs, tq, ts);
    hipLaunchKernelGGL(attn_kernel, dim3(32, 2, 2 * nseg), blk, 0, stream,
                       kT, qT, vq, vs, Opart, Lpart, nseg);
    hipLaunchKernelGGL(attn_combine_kernel, dim3(64, 2, 2), blk, 0, stream,
                       Opart, Lpart, tq, ts, scale, out, Ebf, nseg);
    hipLaunchKernelGGL(conv_kernel, dim3(64, 4, 2), blk, 0, stream,
                       Ebf, wTc, g_cat, be_cat, m_cat, v_cat, out);
}